// Round 1
// baseline (2612.110 us; speedup 1.0000x reference)
//
#include <hip/hip_runtime.h>

#define DIM 768
#define HEADS 12
#define HD 64
#define NB 128
#define NPIECE 16
#define NW 16
#define TOK (NB * NPIECE * NW)   // 32768

// ---------------- LayerNorm over channel dim (one token per block) ----------------
__global__ __launch_bounds__(256) void ln_kernel(const float* __restrict__ x,
                                                 const float* __restrict__ g,
                                                 const float* __restrict__ be,
                                                 float* __restrict__ xn) {
  int t = blockIdx.x;        // token index
  int tid = threadIdx.x;
  const float* row = x + (size_t)t * DIM;
  float v0 = row[tid], v1 = row[tid + 256], v2 = row[tid + 512];
  float s  = v0 + v1 + v2;
  float sq = v0 * v0 + v1 * v1 + v2 * v2;
  #pragma unroll
  for (int off = 32; off; off >>= 1) {
    s  += __shfl_down(s, off);
    sq += __shfl_down(sq, off);
  }
  __shared__ float ls[4], lq[4];
  int wid = tid >> 6, lane = tid & 63;
  if (lane == 0) { ls[wid] = s; lq[wid] = sq; }
  __syncthreads();
  s  = ls[0] + ls[1] + ls[2] + ls[3];
  sq = lq[0] + lq[1] + lq[2] + lq[3];
  float mu  = s * (1.0f / DIM);
  float var = sq * (1.0f / DIM) - mu * mu;
  float rs  = rsqrtf(var + 1e-5f);
  float* orow = xn + (size_t)t * DIM;
  orow[tid]       = (v0 - mu) * rs * g[tid]       + be[tid];
  orow[tid + 256] = (v1 - mu) * rs * g[tid + 256] + be[tid + 256];
  orow[tid + 512] = (v2 - mu) * rs * g[tid + 512] + be[tid + 512];
}

// ---------------- fp32 tiled GEMM: C[M,N] = A[M,K] @ B[K,N] ----------------
// BM=BN=128, BK=8, 256 threads, 8x8 per thread.
// QKV=true: apply relu+eps to columns [0, 2*DIM); QKV=false: add bias.
template <bool QKV>
__global__ __launch_bounds__(256) void gemm_kernel(const float* __restrict__ A,
                                                   const float* __restrict__ Bm,
                                                   const float* __restrict__ bias,
                                                   float* __restrict__ C,
                                                   int M, int N, int K) {
  __shared__ float As[8][128];
  __shared__ float Bs[8][128];
  int t = threadIdx.x;
  int bm = blockIdx.y, bn = blockIdx.x;
  int tx = t & 15, ty = t >> 4;
  const int row0 = bm * 128, col0 = bn * 128;
  float acc[8][8] = {};
  for (int k0 = 0; k0 < K; k0 += 8) {
    // A tile load: thread t -> row t>>1, k-group (t&1)*4
    float4 a4 = *(const float4*)(A + (size_t)(row0 + (t >> 1)) * K + k0 + (t & 1) * 4);
    int ak = (t & 1) * 4, ar = t >> 1;
    As[ak + 0][ar] = a4.x; As[ak + 1][ar] = a4.y; As[ak + 2][ar] = a4.z; As[ak + 3][ar] = a4.w;
    // B tile load: thread t -> k row t>>5, col group (t&31)*4
    float4 b4 = *(const float4*)(Bm + (size_t)(k0 + (t >> 5)) * N + col0 + (t & 31) * 4);
    *(float4*)&Bs[t >> 5][(t & 31) * 4] = b4;
    __syncthreads();
    #pragma unroll
    for (int kk = 0; kk < 8; ++kk) {
      float a[8], b[8];
      *(float4*)&a[0] = *(const float4*)&As[kk][ty * 8];
      *(float4*)&a[4] = *(const float4*)&As[kk][ty * 8 + 4];
      *(float4*)&b[0] = *(const float4*)&Bs[kk][tx * 8];
      *(float4*)&b[4] = *(const float4*)&Bs[kk][tx * 8 + 4];
      #pragma unroll
      for (int i = 0; i < 8; ++i)
        #pragma unroll
        for (int j = 0; j < 8; ++j) acc[i][j] += a[i] * b[j];
    }
    __syncthreads();
  }
  // epilogue
  #pragma unroll
  for (int i = 0; i < 8; ++i) {
    int r = row0 + ty * 8 + i;
    float vals[8];
    #pragma unroll
    for (int j = 0; j < 8; ++j) {
      int c = col0 + tx * 8 + j;
      float v = acc[i][j];
      if constexpr (QKV) {
        if (c < 2 * DIM) v = fmaxf(v, 0.0f) + 1e-6f;   // relu feature map on q,k
      } else {
        v += bias[c];
      }
      vals[j] = v;
    }
    float* dst = C + (size_t)r * N + col0 + tx * 8;
    *(float4*)dst       = *(float4*)&vals[0];
    *(float4*)(dst + 4) = *(float4*)&vals[4];
  }
}

// ---------------- fused attention middle ----------------
// out_i = sum_j wp[i][j] * (q_i @ k_j^T) @ v_j   per (b, h, i); block = (b,h,i)
__global__ __launch_bounds__(256) void attn_kernel(const float* __restrict__ qkv,
                                                   const float* __restrict__ wp,
                                                   float* __restrict__ attn) {
  int idx = blockIdx.x;
  int i = idx & 15;
  int h = (idx >> 4) % HEADS;
  int b = idx >> 4;  b /= HEADS;
  __shared__ float qs[16][68], ks[16][68], vs[16][68], As[16][68];
  int t = threadIdx.x;
  {  // load q_i  [16 w][64 d]
    int w = t >> 4, d4 = (t & 15) * 4;
    const float* src = qkv + (size_t)((b * 16 + i) * 16 + w) * (3 * DIM) + h * HD + d4;
    float4 v4 = *(const float4*)src;
    qs[w][d4] = v4.x; qs[w][d4 + 1] = v4.y; qs[w][d4 + 2] = v4.z; qs[w][d4 + 3] = v4.w;
  }
  int e = t & 63, w0 = t >> 6;
  float acc[4] = {0.f, 0.f, 0.f, 0.f};
  for (int j = 0; j < 16; ++j) {
    __syncthreads();   // prior-iteration readers of ks/vs/As done
    {
      int w = t >> 4, d4 = (t & 15) * 4;
      const float* base = qkv + (size_t)((b * 16 + j) * 16 + w) * (3 * DIM) + h * HD + d4;
      float4 k4 = *(const float4*)(base + DIM);
      ks[w][d4] = k4.x; ks[w][d4 + 1] = k4.y; ks[w][d4 + 2] = k4.z; ks[w][d4 + 3] = k4.w;
      float4 v4 = *(const float4*)(base + 2 * DIM);
      vs[w][d4] = v4.x; vs[w][d4 + 1] = v4.y; vs[w][d4 + 2] = v4.z; vs[w][d4 + 3] = v4.w;
    }
    __syncthreads();
    {  // A[w][u] = dot(q_i row w, k_j row u) — one element per thread
      int w = t >> 4, u = t & 15;
      float s = 0.f;
      #pragma unroll
      for (int d4 = 0; d4 < 64; d4 += 4) {
        float4 qa = *(const float4*)&qs[w][d4];
        float4 kb = *(const float4*)&ks[u][d4];
        s += qa.x * kb.x + qa.y * kb.y + qa.z * kb.z + qa.w * kb.w;
      }
      As[w][u] = s;
    }
    __syncthreads();
    float wpij = wp[i * 16 + j];
    #pragma unroll
    for (int r = 0; r < 4; ++r) {
      int w = w0 + 4 * r;
      float s = 0.f;
      #pragma unroll
      for (int u = 0; u < 16; ++u) s += As[w][u] * vs[u][e];
      acc[r] += wpij * s;
    }
  }
  #pragma unroll
  for (int r = 0; r < 4; ++r) {
    int w = w0 + 4 * r;
    attn[(size_t)((b * 16 + i) * 16 + w) * DIM + h * HD + e] = acc[r];
  }
}

extern "C" void kernel_launch(void* const* d_in, const int* in_sizes, int n_in,
                              void* d_out, int out_size, void* d_ws, size_t ws_size,
                              hipStream_t stream) {
  const float* x    = (const float*)d_in[0];
  const float* g    = (const float*)d_in[1];
  const float* be   = (const float*)d_in[2];
  const float* wqkv = (const float*)d_in[3];
  const float* wout = (const float*)d_in[4];
  const float* bout = (const float*)d_in[5];
  const float* wp   = (const float*)d_in[6];
  float* out = (float*)d_out;

  float* xn   = (float*)d_ws;                    // TOK*DIM fp32
  float* qkv  = xn + (size_t)TOK * DIM;          // TOK*3*DIM fp32
  float* attn = xn;                              // reuse xn region (dead after QKV GEMM)

  ln_kernel<<<TOK, 256, 0, stream>>>(x, g, be, xn);

  dim3 g1(3 * DIM / 128, TOK / 128);
  gemm_kernel<true><<<g1, 256, 0, stream>>>(xn, wqkv, nullptr, qkv, TOK, 3 * DIM, DIM);

  attn_kernel<<<NB * HEADS * NPIECE, 256, 0, stream>>>(qkv, wp, attn);

  dim3 g2(DIM / 128, TOK / 128);
  gemm_kernel<false><<<g2, 256, 0, stream>>>(attn, wout, bout, out, TOK, DIM, DIM);
}

// Round 2
// 1119.560 us; speedup vs baseline: 2.3332x; 2.3332x over previous
//
#include <hip/hip_runtime.h>

#define DIM 768
#define HEADS 12
#define HD 64
#define NB 128
#define NPIECE 16
#define NW 16
#define TOK (NB * NPIECE * NW)   // 32768

typedef unsigned short ushort_t;
typedef __attribute__((ext_vector_type(8))) short short8v;   // 8 bf16 = 4 VGPRs
typedef __attribute__((ext_vector_type(4))) float f32x4;

__device__ __forceinline__ ushort_t f2bf(float x) {
  union { float f; unsigned u; } c; c.f = x;
  unsigned r = (c.u + 0x7FFFu + ((c.u >> 16) & 1u)) >> 16;
  return (ushort_t)r;
}

__device__ __forceinline__ void gload_lds16(const void* g, void* l) {
  __builtin_amdgcn_global_load_lds((const __attribute__((address_space(1))) void*)g,
                                   (__attribute__((address_space(3))) void*)l, 16, 0, 0);
}

// ---------------- LayerNorm -> bf16 ----------------
__global__ __launch_bounds__(256) void ln_kernel(const float* __restrict__ x,
                                                 const float* __restrict__ g,
                                                 const float* __restrict__ be,
                                                 ushort_t* __restrict__ xn) {
  int t = blockIdx.x;
  int tid = threadIdx.x;
  const float* row = x + (size_t)t * DIM;
  float v0 = row[tid], v1 = row[tid + 256], v2 = row[tid + 512];
  float s  = v0 + v1 + v2;
  float sq = v0 * v0 + v1 * v1 + v2 * v2;
  #pragma unroll
  for (int off = 32; off; off >>= 1) {
    s  += __shfl_down(s, off);
    sq += __shfl_down(sq, off);
  }
  __shared__ float ls[4], lq[4];
  int wid = tid >> 6, lane = tid & 63;
  if (lane == 0) { ls[wid] = s; lq[wid] = sq; }
  __syncthreads();
  s  = ls[0] + ls[1] + ls[2] + ls[3];
  sq = lq[0] + lq[1] + lq[2] + lq[3];
  float mu  = s * (1.0f / DIM);
  float var = sq * (1.0f / DIM) - mu * mu;
  float rs  = rsqrtf(var + 1e-5f);
  ushort_t* orow = xn + (size_t)t * DIM;
  orow[tid]       = f2bf((v0 - mu) * rs * g[tid]       + be[tid]);
  orow[tid + 256] = f2bf((v1 - mu) * rs * g[tid + 256] + be[tid + 256]);
  orow[tid + 512] = f2bf((v2 - mu) * rs * g[tid + 512] + be[tid + 512]);
}

// ---------------- weight transpose + bf16 convert: dst[c][r] = bf16(src[r][c]) ----------------
__global__ __launch_bounds__(256) void convT(const float* __restrict__ src,
                                             ushort_t* __restrict__ dst, int R, int Ccol) {
  __shared__ float tile[32][33];
  int c0 = blockIdx.x * 32, r0 = blockIdx.y * 32;
  int tx = threadIdx.x & 31, ty = threadIdx.x >> 5;  // 32x8
  #pragma unroll
  for (int i = 0; i < 32; i += 8)
    tile[ty + i][tx] = src[(size_t)(r0 + ty + i) * Ccol + c0 + tx];
  __syncthreads();
  #pragma unroll
  for (int i = 0; i < 32; i += 8)
    dst[(size_t)(c0 + ty + i) * R + r0 + tx] = f2bf(tile[tx][ty + i]);
}

// ---------------- bf16 MFMA GEMM (m97 structure): C[M,N] = A[M,K] @ Bt[N,K]^T ----------------
// 128x128 tile, BK=32, 256 threads (4 waves, 2x2), 4x4 16x16x32 frags per wave.
template <bool QKV>
__global__ __launch_bounds__(256) void gemm_mfma(const ushort_t* __restrict__ A,
                                                 const ushort_t* __restrict__ Bt,
                                                 const float* __restrict__ bias,
                                                 float* __restrict__ C,
                                                 int M, int N, int K, int nbn) {
  __shared__ __align__(16) ushort_t Al[128 * 32];
  __shared__ __align__(16) ushort_t Bl[128 * 32];
  // XCD-aware bijective swizzle (gridDim.x % 8 == 0)
  int bid = blockIdx.x;
  int q = gridDim.x >> 3;
  int wid = (bid & 7) * q + (bid >> 3);
  int bm = wid / nbn, bn = wid % nbn;
  int row0 = bm * 128, col0 = bn * 128;
  int t = threadIdx.x;
  int lane = t & 63, wave = t >> 6;
  int wr = wave >> 1, wc = wave & 1;

  // staging: thread t covers LDS bytes [t*16, t*16+16) of each 4KB half-tile
  int srow = t >> 2;            // 0..63
  int sk8  = (t & 3) * 8;       // k element offset
  const ushort_t* Ag = A + (size_t)(row0 + srow) * K + sk8;
  const ushort_t* Bg = Bt + (size_t)(col0 + srow) * K + sk8;
  ushort_t* Ald = &Al[srow * 32 + sk8];
  ushort_t* Bld = &Bl[srow * 32 + sk8];

  // fragment read base: row = wr*64 + m*16 + (lane&15), k = (lane>>4)*8
  int fr = lane & 15, fk = (lane >> 4) * 8;
  const ushort_t* Afr = &Al[(wr * 64 + fr) * 32 + fk];
  const ushort_t* Bfr = &Bl[(wc * 64 + fr) * 32 + fk];

  f32x4 acc[4][4] = {};
  for (int k0 = 0; k0 < K; k0 += 32) {
    gload_lds16(Ag + k0, Ald);
    gload_lds16(Ag + (size_t)64 * K + k0, Ald + 64 * 32);
    gload_lds16(Bg + k0, Bld);
    gload_lds16(Bg + (size_t)64 * K + k0, Bld + 64 * 32);
    __syncthreads();
    short8v a[4], b[4];
    #pragma unroll
    for (int m = 0; m < 4; ++m) a[m] = *(const short8v*)(Afr + m * 16 * 32);
    #pragma unroll
    for (int n = 0; n < 4; ++n) b[n] = *(const short8v*)(Bfr + n * 16 * 32);
    #pragma unroll
    for (int m = 0; m < 4; ++m)
      #pragma unroll
      for (int n = 0; n < 4; ++n)
        acc[m][n] = __builtin_amdgcn_mfma_f32_16x16x32_bf16(a[m], b[n], acc[m][n], 0, 0, 0);
    __syncthreads();
  }
  // epilogue: C/D layout col = lane&15, row = (lane>>4)*4 + j
  int rbase = row0 + wr * 64 + ((lane >> 4) << 2);
  int cbase = col0 + wc * 64 + (lane & 15);
  #pragma unroll
  for (int m = 0; m < 4; ++m) {
    #pragma unroll
    for (int n = 0; n < 4; ++n) {
      int c = cbase + n * 16;
      #pragma unroll
      for (int j = 0; j < 4; ++j) {
        int r = rbase + m * 16 + j;
        float v = acc[m][n][j];
        if constexpr (QKV) {
          if (c < 2 * DIM) v = fmaxf(v, 0.0f) + 1e-6f;
        } else {
          v += bias[c];
        }
        C[(size_t)r * N + c] = v;
      }
    }
  }
}

// ---------------- fused attention middle (fp32 math, bf16 out) ----------------
// out_i = sum_j wp[i][j] * (q_i @ k_j^T) @ v_j   per (b, h, i)
__global__ __launch_bounds__(256) void attn_kernel(const float* __restrict__ qkv,
                                                   const float* __restrict__ wp,
                                                   ushort_t* __restrict__ attnO) {
  // XCD swizzle: same-(b,h) groups (16 consecutive work ids) stay on one XCD
  int bid = blockIdx.x;
  int q = gridDim.x >> 3;                     // 24576/8 = 3072
  int idx = (bid & 7) * q + (bid >> 3);
  int i = idx & 15;
  int h = (idx >> 4) % HEADS;
  int b = (idx >> 4) / HEADS;
  __shared__ float qs[16][68], ks[16][68], vs[16][68], As[16][68];
  int t = threadIdx.x;
  {
    int w = t >> 4, d4 = (t & 15) * 4;
    const float* src = qkv + (size_t)((b * 16 + i) * 16 + w) * (3 * DIM) + h * HD + d4;
    float4 v4 = *(const float4*)src;
    qs[w][d4] = v4.x; qs[w][d4 + 1] = v4.y; qs[w][d4 + 2] = v4.z; qs[w][d4 + 3] = v4.w;
  }
  int e = t & 63, w0 = t >> 6;
  float acc[4] = {0.f, 0.f, 0.f, 0.f};
  for (int j = 0; j < 16; ++j) {
    __syncthreads();
    {
      int w = t >> 4, d4 = (t & 15) * 4;
      const float* base = qkv + (size_t)((b * 16 + j) * 16 + w) * (3 * DIM) + h * HD + d4;
      float4 k4 = *(const float4*)(base + DIM);
      ks[w][d4] = k4.x; ks[w][d4 + 1] = k4.y; ks[w][d4 + 2] = k4.z; ks[w][d4 + 3] = k4.w;
      float4 v4 = *(const float4*)(base + 2 * DIM);
      vs[w][d4] = v4.x; vs[w][d4 + 1] = v4.y; vs[w][d4 + 2] = v4.z; vs[w][d4 + 3] = v4.w;
    }
    __syncthreads();
    {
      int w = t >> 4, u = t & 15;
      float s = 0.f;
      #pragma unroll
      for (int d4 = 0; d4 < 64; d4 += 4) {
        float4 qa = *(const float4*)&qs[w][d4];
        float4 kb = *(const float4*)&ks[u][d4];
        s += qa.x * kb.x + qa.y * kb.y + qa.z * kb.z + qa.w * kb.w;
      }
      As[w][u] = s;
    }
    __syncthreads();
    float wpij = wp[i * 16 + j];
    #pragma unroll
    for (int r = 0; r < 4; ++r) {
      int w = w0 + 4 * r;
      float s = 0.f;
      #pragma unroll
      for (int u = 0; u < 16; ++u) s += As[w][u] * vs[u][e];
      acc[r] += wpij * s;
    }
  }
  #pragma unroll
  for (int r = 0; r < 4; ++r) {
    int w = w0 + 4 * r;
    attnO[(size_t)((b * 16 + i) * 16 + w) * DIM + h * HD + e] = f2bf(acc[r]);
  }
}

extern "C" void kernel_launch(void* const* d_in, const int* in_sizes, int n_in,
                              void* d_out, int out_size, void* d_ws, size_t ws_size,
                              hipStream_t stream) {
  const float* x    = (const float*)d_in[0];
  const float* g    = (const float*)d_in[1];
  const float* be   = (const float*)d_in[2];
  const float* wqkv = (const float*)d_in[3];
  const float* wout = (const float*)d_in[4];
  const float* bout = (const float*)d_in[5];
  const float* wp   = (const float*)d_in[6];
  float* out = (float*)d_out;

  char* w = (char*)d_ws;
  float*    qkv   = (float*)w;                           // 301,989,888 B
  ushort_t* xn    = (ushort_t*)(w + 301989888);          //  50,331,648 B (reused as attnO)
  ushort_t* wqkvT = (ushort_t*)(w + 352321536);          //   3,538,944 B
  ushort_t* woutT = (ushort_t*)(w + 355860480);          //   1,179,648 B
  ushort_t* attnO = xn;                                  // xn dead after GEMM1

  dim3 gt1(3 * DIM / 32, DIM / 32);
  convT<<<gt1, 256, 0, stream>>>(wqkv, wqkvT, DIM, 3 * DIM);
  dim3 gt2(DIM / 32, DIM / 32);
  convT<<<gt2, 256, 0, stream>>>(wout, woutT, DIM, DIM);

  ln_kernel<<<TOK, 256, 0, stream>>>(x, g, be, xn);

  gemm_mfma<true><<<(TOK / 128) * (3 * DIM / 128), 256, 0, stream>>>(
      xn, wqkvT, nullptr, qkv, TOK, 3 * DIM, DIM, 3 * DIM / 128);

  attn_kernel<<<NB * HEADS * NPIECE, 256, 0, stream>>>(qkv, wp, attnO);

  gemm_mfma<false><<<(TOK / 128) * (DIM / 128), 256, 0, stream>>>(
      attnO, woutT, bout, out, TOK, DIM, DIM, DIM / 128);
}

// Round 3
// 358.435 us; speedup vs baseline: 7.2875x; 3.1235x over previous
//
#include <hip/hip_runtime.h>

#define DIM 768
#define HEADS 12
#define TOK 32768

typedef unsigned short ushort_t;
typedef __attribute__((ext_vector_type(8))) short short8v;   // 8 bf16
typedef __attribute__((ext_vector_type(4))) float f32x4;
typedef __attribute__((ext_vector_type(4))) unsigned short us4;

__device__ __forceinline__ ushort_t f2bf(float x) {
  union { float f; unsigned u; } c; c.f = x;
  unsigned r = (c.u + 0x7FFFu + ((c.u >> 16) & 1u)) >> 16;
  return (ushort_t)r;
}

__device__ __forceinline__ void gload_lds16(const void* g, void* l) {
  __builtin_amdgcn_global_load_lds((const __attribute__((address_space(1))) void*)g,
                                   (__attribute__((address_space(3))) void*)l, 16, 0, 0);
}

// ---------------- LayerNorm -> bf16 ----------------
__global__ __launch_bounds__(256) void ln_kernel(const float* __restrict__ x,
                                                 const float* __restrict__ g,
                                                 const float* __restrict__ be,
                                                 ushort_t* __restrict__ xn) {
  int t = blockIdx.x;
  int tid = threadIdx.x;
  const float* row = x + (size_t)t * DIM;
  float v0 = row[tid], v1 = row[tid + 256], v2 = row[tid + 512];
  float s  = v0 + v1 + v2;
  float sq = v0 * v0 + v1 * v1 + v2 * v2;
  #pragma unroll
  for (int off = 32; off; off >>= 1) {
    s  += __shfl_down(s, off);
    sq += __shfl_down(sq, off);
  }
  __shared__ float ls[4], lq[4];
  int wid = tid >> 6, lane = tid & 63;
  if (lane == 0) { ls[wid] = s; lq[wid] = sq; }
  __syncthreads();
  s  = ls[0] + ls[1] + ls[2] + ls[3];
  sq = lq[0] + lq[1] + lq[2] + lq[3];
  float mu  = s * (1.0f / DIM);
  float var = sq * (1.0f / DIM) - mu * mu;
  float rs  = rsqrtf(var + 1e-5f);
  ushort_t* orow = xn + (size_t)t * DIM;
  orow[tid]       = f2bf((v0 - mu) * rs * g[tid]       + be[tid]);
  orow[tid + 256] = f2bf((v1 - mu) * rs * g[tid + 256] + be[tid + 256]);
  orow[tid + 512] = f2bf((v2 - mu) * rs * g[tid + 512] + be[tid + 512]);
}

// ---------------- weight transpose + bf16: dst[c][r] = bf16(src[r][c]) ----------------
__global__ __launch_bounds__(256) void convT(const float* __restrict__ src,
                                             ushort_t* __restrict__ dst, int R, int Ccol) {
  __shared__ float tile[32][33];
  int c0 = blockIdx.x * 32, r0 = blockIdx.y * 32;
  int tx = threadIdx.x & 31, ty = threadIdx.x >> 5;
  #pragma unroll
  for (int i = 0; i < 32; i += 8)
    tile[ty + i][tx] = src[(size_t)(r0 + ty + i) * Ccol + c0 + tx];
  __syncthreads();
  #pragma unroll
  for (int i = 0; i < 32; i += 8)
    dst[(size_t)(c0 + ty + i) * R + r0 + tx] = f2bf(tile[tx][ty + i]);
}

// ---------------- GEMM1: qkv projection, split epilogue -> q, k, vT (all bf16) ----------------
__global__ __launch_bounds__(256) void gemm_qkv(const ushort_t* __restrict__ A,
                                                const ushort_t* __restrict__ Bt,
                                                ushort_t* __restrict__ qbf,
                                                ushort_t* __restrict__ kbf,
                                                ushort_t* __restrict__ vTbf) {
  const int N = 3 * DIM, K = DIM;
  __shared__ __align__(16) ushort_t Al[128 * 32];
  __shared__ __align__(16) ushort_t Bl[128 * 32];
  int bid = blockIdx.x;
  int qd = gridDim.x >> 3;
  int wid = (bid & 7) * qd + (bid >> 3);
  const int nbn = N / 128;   // 18
  int bm = wid / nbn, bn = wid % nbn;
  int row0 = bm * 128, col0 = bn * 128;
  int t = threadIdx.x;
  int lane = t & 63, wave = t >> 6;
  int wr = wave >> 1, wc = wave & 1;

  int srow = t >> 2;
  int sk8  = (t & 3) * 8;
  const ushort_t* Ag = A + (size_t)(row0 + srow) * K + sk8;
  const ushort_t* Bg = Bt + (size_t)(col0 + srow) * K + sk8;
  ushort_t* Ald = &Al[srow * 32 + sk8];
  ushort_t* Bld = &Bl[srow * 32 + sk8];

  int fr = lane & 15, fk = (lane >> 4) * 8;
  const ushort_t* Afr = &Al[(wr * 64 + fr) * 32 + fk];
  const ushort_t* Bfr = &Bl[(wc * 64 + fr) * 32 + fk];

  f32x4 acc[4][4] = {};
  for (int k0 = 0; k0 < K; k0 += 32) {
    gload_lds16(Ag + k0, Ald);
    gload_lds16(Ag + (size_t)64 * K + k0, Ald + 64 * 32);
    gload_lds16(Bg + k0, Bld);
    gload_lds16(Bg + (size_t)64 * K + k0, Bld + 64 * 32);
    __syncthreads();
    short8v a[4], b[4];
    #pragma unroll
    for (int m = 0; m < 4; ++m) a[m] = *(const short8v*)(Afr + m * 16 * 32);
    #pragma unroll
    for (int n = 0; n < 4; ++n) b[n] = *(const short8v*)(Bfr + n * 16 * 32);
    #pragma unroll
    for (int m = 0; m < 4; ++m)
      #pragma unroll
      for (int n = 0; n < 4; ++n)
        acc[m][n] = __builtin_amdgcn_mfma_f32_16x16x32_bf16(a[m], b[n], acc[m][n], 0, 0, 0);
    __syncthreads();
  }
  int rbase = row0 + wr * 64 + ((lane >> 4) << 2);
  int cbase = col0 + wc * 64 + fr;
  #pragma unroll
  for (int m = 0; m < 4; ++m) {
    int r0r = rbase + m * 16;
    #pragma unroll
    for (int n = 0; n < 4; ++n) {
      int c = cbase + n * 16;
      if (c < DIM) {
        #pragma unroll
        for (int j = 0; j < 4; ++j)
          qbf[(size_t)(r0r + j) * DIM + c] = f2bf(fmaxf(acc[m][n][j], 0.0f) + 1e-6f);
      } else if (c < 2 * DIM) {
        #pragma unroll
        for (int j = 0; j < 4; ++j)
          kbf[(size_t)(r0r + j) * DIM + (c - DIM)] = f2bf(fmaxf(acc[m][n][j], 0.0f) + 1e-6f);
      } else {
        int ch = c - 2 * DIM;
        int hh = ch >> 6, e = ch & 63;
        int bb = r0r >> 8, rr = r0r & 255;
        us4 pk;
        #pragma unroll
        for (int j = 0; j < 4; ++j) pk[j] = f2bf(acc[m][n][j]);
        *(us4*)&vTbf[((((size_t)bb * HEADS + hh) * 64 + e) << 8) + rr] = pk;
      }
    }
  }
}

// ---------------- fused attention middle: per (b,h), full MFMA ----------------
// S = Q@K^T (per 64-row quarter), S' = wp[i,j]*S (bf16), out = S'@V via vT.
__global__ __launch_bounds__(512) void attn_fused(const ushort_t* __restrict__ qbf,
                                                  const ushort_t* __restrict__ kbf,
                                                  const ushort_t* __restrict__ vTbf,
                                                  const float* __restrict__ wp,
                                                  ushort_t* __restrict__ attnO) {
  __shared__ __align__(16) char lds[65536];
  // [0:32768): K rows(256x128B) phase1 / VT rows(64x512B) phase2 — XOR-swizzled
  // [32768:65536): Q quarter (64x128B) phase1 / S' (64x512B) phase2
  int bh = blockIdx.x;
  int b = bh / HEADS, h = bh % HEADS;
  int t = threadIdx.x;
  int lane = t & 63, wave = t >> 6;
  int wr = wave >> 2, wc = wave & 3;       // 2 x 4
  int fr = lane & 15, fkb = (lane >> 4) << 4;   // k byte sub-offset 0/16/32/48

  const char* qg = (const char*)(qbf + ((size_t)b * 256) * DIM + h * 64);
  const char* kg = (const char*)(kbf + ((size_t)b * 256) * DIM + h * 64);
  const char* vg = (const char*)(vTbf + ((size_t)bh << 14));   // [64][256] bf16, 32KB

  for (int q4 = 0; q4 < 4; ++q4) {
    // ---- stage K (256x64 bf16) + Q quarter, source pre-swizzled ----
    #pragma unroll
    for (int is = 0; is < 4; ++is) {
      int o = is * 8192 + t * 16;
      int r = o >> 7;
      int byt = (o & 127) ^ ((r & 7) << 4);
      gload_lds16(kg + (size_t)r * (DIM * 2) + byt, lds + o);
    }
    {
      int o = t * 16;
      int r = o >> 7;
      int byt = (o & 127) ^ ((r & 7) << 4);
      gload_lds16(qg + (size_t)(q4 * 64 + r) * (DIM * 2) + byt, lds + 32768 + o);
    }
    __syncthreads();
    // ---- GEMM A: S_q[64][256], K-dim 64 ----
    f32x4 accA[2][4] = {};
    {
      short8v af[2][2], bfv[4][2];
      #pragma unroll
      for (int mt = 0; mt < 2; ++mt)
        #pragma unroll
        for (int ks = 0; ks < 2; ++ks) {
          int r = wr * 32 + mt * 16 + fr;
          int kb = ks * 64 + fkb;
          af[mt][ks] = *(const short8v*)(lds + 32768 + r * 128 + (kb ^ ((r & 7) << 4)));
        }
      #pragma unroll
      for (int nt = 0; nt < 4; ++nt)
        #pragma unroll
        for (int ks = 0; ks < 2; ++ks) {
          int c = wc * 64 + nt * 16 + fr;
          int kb = ks * 64 + fkb;
          bfv[nt][ks] = *(const short8v*)(lds + c * 128 + (kb ^ ((c & 7) << 4)));
        }
      #pragma unroll
      for (int mt = 0; mt < 2; ++mt)
        #pragma unroll
        for (int nt = 0; nt < 4; ++nt)
          #pragma unroll
          for (int ks = 0; ks < 2; ++ks)
            accA[mt][nt] = __builtin_amdgcn_mfma_f32_16x16x32_bf16(af[mt][ks], bfv[nt][ks],
                                                                   accA[mt][nt], 0, 0, 0);
    }
    // scale by wp (wave-uniform per tile) -> bf16 in regs
    ushort_t sv[2][4][4];
    #pragma unroll
    for (int mt = 0; mt < 2; ++mt)
      #pragma unroll
      for (int nt = 0; nt < 4; ++nt) {
        float wpf = wp[(q4 * 4 + wr * 2 + mt) * 16 + (wc * 4 + nt)];
        #pragma unroll
        for (int j = 0; j < 4; ++j) sv[mt][nt][j] = f2bf(accA[mt][nt][j] * wpf);
      }
    __syncthreads();          // all K/Q reads complete before overwrite
    // ---- write S' (swizzled) + stage VT over K region ----
    #pragma unroll
    for (int mt = 0; mt < 2; ++mt)
      #pragma unroll
      for (int nt = 0; nt < 4; ++nt)
        #pragma unroll
        for (int j = 0; j < 4; ++j) {
          int rs = wr * 32 + mt * 16 + ((lane >> 4) << 2) + j;
          int cs = wc * 64 + nt * 16 + fr;
          *(ushort_t*)(lds + 32768 + rs * 512 + ((cs * 2) ^ ((rs & 7) << 4))) = sv[mt][nt][j];
        }
    #pragma unroll
    for (int is = 0; is < 4; ++is) {
      int o = is * 8192 + t * 16;
      int e = o >> 9;
      int byt = (o & 511) ^ ((e & 7) << 4);
      gload_lds16(vg + e * 512 + byt, lds + o);
    }
    __syncthreads();
    // ---- GEMM B: out_q[64][64], K-dim 256 ----
    f32x4 accB[2] = {{0.f,0.f,0.f,0.f},{0.f,0.f,0.f,0.f}};
    #pragma unroll
    for (int ks = 0; ks < 8; ++ks) {
      int kb = ks * 64 + fkb;
      int e = wc * 16 + fr;
      short8v bv = *(const short8v*)(lds + e * 512 + (kb ^ ((e & 7) << 4)));
      #pragma unroll
      for (int mt = 0; mt < 2; ++mt) {
        int r = wr * 32 + mt * 16 + fr;
        short8v av = *(const short8v*)(lds + 32768 + r * 512 + (kb ^ ((r & 7) << 4)));
        accB[mt] = __builtin_amdgcn_mfma_f32_16x16x32_bf16(av, bv, accB[mt], 0, 0, 0);
      }
    }
    #pragma unroll
    for (int mt = 0; mt < 2; ++mt) {
      int row = b * 256 + q4 * 64 + wr * 32 + mt * 16 + ((lane >> 4) << 2);
      int col = h * 64 + wc * 16 + fr;
      #pragma unroll
      for (int j = 0; j < 4; ++j)
        attnO[(size_t)(row + j) * DIM + col] = f2bf(accB[mt][j]);
    }
    __syncthreads();          // protect regions before next quarter
  }
}

// ---------------- GEMM2: out = attnO @ woutT^T + bias (fp32 out) ----------------
__global__ __launch_bounds__(256) void gemm_out(const ushort_t* __restrict__ A,
                                                const ushort_t* __restrict__ Bt,
                                                const float* __restrict__ bias,
                                                float* __restrict__ C) {
  const int N = DIM, K = DIM;
  __shared__ __align__(16) ushort_t Al[128 * 32];
  __shared__ __align__(16) ushort_t Bl[128 * 32];
  int bid = blockIdx.x;
  int qd = gridDim.x >> 3;
  int wid = (bid & 7) * qd + (bid >> 3);
  const int nbn = N / 128;   // 6
  int bm = wid / nbn, bn = wid % nbn;
  int row0 = bm * 128, col0 = bn * 128;
  int t = threadIdx.x;
  int lane = t & 63, wave = t >> 6;
  int wr = wave >> 1, wc = wave & 1;

  int srow = t >> 2;
  int sk8  = (t & 3) * 8;
  const ushort_t* Ag = A + (size_t)(row0 + srow) * K + sk8;
  const ushort_t* Bg = Bt + (size_t)(col0 + srow) * K + sk8;
  ushort_t* Ald = &Al[srow * 32 + sk8];
  ushort_t* Bld = &Bl[srow * 32 + sk8];

  int fr = lane & 15, fk = (lane >> 4) * 8;
  const ushort_t* Afr = &Al[(wr * 64 + fr) * 32 + fk];
  const ushort_t* Bfr = &Bl[(wc * 64 + fr) * 32 + fk];

  f32x4 acc[4][4] = {};
  for (int k0 = 0; k0 < K; k0 += 32) {
    gload_lds16(Ag + k0, Ald);
    gload_lds16(Ag + (size_t)64 * K + k0, Ald + 64 * 32);
    gload_lds16(Bg + k0, Bld);
    gload_lds16(Bg + (size_t)64 * K + k0, Bld + 64 * 32);
    __syncthreads();
    short8v a[4], b[4];
    #pragma unroll
    for (int m = 0; m < 4; ++m) a[m] = *(const short8v*)(Afr + m * 16 * 32);
    #pragma unroll
    for (int n = 0; n < 4; ++n) b[n] = *(const short8v*)(Bfr + n * 16 * 32);
    #pragma unroll
    for (int m = 0; m < 4; ++m)
      #pragma unroll
      for (int n = 0; n < 4; ++n)
        acc[m][n] = __builtin_amdgcn_mfma_f32_16x16x32_bf16(a[m], b[n], acc[m][n], 0, 0, 0);
    __syncthreads();
  }
  int rbase = row0 + wr * 64 + ((lane >> 4) << 2);
  int cbase = col0 + wc * 64 + fr;
  #pragma unroll
  for (int m = 0; m < 4; ++m) {
    #pragma unroll
    for (int n = 0; n < 4; ++n) {
      int c = cbase + n * 16;
      float bz = bias[c];
      #pragma unroll
      for (int j = 0; j < 4; ++j)
        C[(size_t)(rbase + m * 16 + j) * N + c] = acc[m][n][j] + bz;
    }
  }
}

extern "C" void kernel_launch(void* const* d_in, const int* in_sizes, int n_in,
                              void* d_out, int out_size, void* d_ws, size_t ws_size,
                              hipStream_t stream) {
  const float* x    = (const float*)d_in[0];
  const float* g    = (const float*)d_in[1];
  const float* be   = (const float*)d_in[2];
  const float* wqkv = (const float*)d_in[3];
  const float* wout = (const float*)d_in[4];
  const float* bout = (const float*)d_in[5];
  const float* wp   = (const float*)d_in[6];
  float* out = (float*)d_out;

  char* w = (char*)d_ws;
  const size_t SZ = (size_t)TOK * DIM * 2;       // 50,331,648 B
  ushort_t* qbf   = (ushort_t*)(w);
  ushort_t* kbf   = (ushort_t*)(w + SZ);
  ushort_t* vTbf  = (ushort_t*)(w + 2 * SZ);
  ushort_t* xn    = (ushort_t*)(w + 3 * SZ);     // reused as attnO
  ushort_t* wqkvT = (ushort_t*)(w + 4 * SZ);
  ushort_t* woutT = (ushort_t*)(w + 4 * SZ + 3538944);
  ushort_t* attnO = xn;

  dim3 gt1(3 * DIM / 32, DIM / 32);
  convT<<<gt1, 256, 0, stream>>>(wqkv, wqkvT, DIM, 3 * DIM);
  dim3 gt2(DIM / 32, DIM / 32);
  convT<<<gt2, 256, 0, stream>>>(wout, woutT, DIM, DIM);

  ln_kernel<<<TOK, 256, 0, stream>>>(x, g, be, xn);

  gemm_qkv<<<(TOK / 128) * (3 * DIM / 128), 256, 0, stream>>>(xn, wqkvT, qbf, kbf, vTbf);

  attn_fused<<<128 * HEADS, 512, 0, stream>>>(qbf, kbf, vTbf, wp, attnO);

  gemm_out<<<(TOK / 128) * (DIM / 128), 256, 0, stream>>>(attnO, woutT, bout, out);
}

// Round 4
// 333.536 us; speedup vs baseline: 7.8316x; 1.0747x over previous
//
#include <hip/hip_runtime.h>

#define DIM 768
#define HEADS 12
#define TOK 32768

typedef unsigned short ushort_t;
typedef __attribute__((ext_vector_type(8))) short short8v;   // 8 bf16
typedef __attribute__((ext_vector_type(4))) float f32x4;
typedef __attribute__((ext_vector_type(4))) unsigned short us4;

__device__ __forceinline__ ushort_t f2bf(float x) {
  union { float f; unsigned u; } c; c.f = x;
  unsigned r = (c.u + 0x7FFFu + ((c.u >> 16) & 1u)) >> 16;
  return (ushort_t)r;
}

__device__ __forceinline__ void gload_lds16(const void* g, void* l) {
  __builtin_amdgcn_global_load_lds((const __attribute__((address_space(1))) void*)g,
                                   (__attribute__((address_space(3))) void*)l, 16, 0, 0);
}

// ---------------- LayerNorm -> bf16 ----------------
__global__ __launch_bounds__(256) void ln_kernel(const float* __restrict__ x,
                                                 const float* __restrict__ g,
                                                 const float* __restrict__ be,
                                                 ushort_t* __restrict__ xn) {
  int t = blockIdx.x;
  int tid = threadIdx.x;
  const float* row = x + (size_t)t * DIM;
  float v0 = row[tid], v1 = row[tid + 256], v2 = row[tid + 512];
  float s  = v0 + v1 + v2;
  float sq = v0 * v0 + v1 * v1 + v2 * v2;
  #pragma unroll
  for (int off = 32; off; off >>= 1) {
    s  += __shfl_down(s, off);
    sq += __shfl_down(sq, off);
  }
  __shared__ float ls[4], lq[4];
  int wid = tid >> 6, lane = tid & 63;
  if (lane == 0) { ls[wid] = s; lq[wid] = sq; }
  __syncthreads();
  s  = ls[0] + ls[1] + ls[2] + ls[3];
  sq = lq[0] + lq[1] + lq[2] + lq[3];
  float mu  = s * (1.0f / DIM);
  float var = sq * (1.0f / DIM) - mu * mu;
  float rs  = rsqrtf(var + 1e-5f);
  ushort_t* orow = xn + (size_t)t * DIM;
  orow[tid]       = f2bf((v0 - mu) * rs * g[tid]       + be[tid]);
  orow[tid + 256] = f2bf((v1 - mu) * rs * g[tid + 256] + be[tid + 256]);
  orow[tid + 512] = f2bf((v2 - mu) * rs * g[tid + 512] + be[tid + 512]);
}

// ---------------- weight transpose + bf16: dst[c][r] = bf16(src[r][c]) ----------------
__global__ __launch_bounds__(256) void convT(const float* __restrict__ src,
                                             ushort_t* __restrict__ dst, int R, int Ccol) {
  __shared__ float tile[32][33];
  int c0 = blockIdx.x * 32, r0 = blockIdx.y * 32;
  int tx = threadIdx.x & 31, ty = threadIdx.x >> 5;
  #pragma unroll
  for (int i = 0; i < 32; i += 8)
    tile[ty + i][tx] = src[(size_t)(r0 + ty + i) * Ccol + c0 + tx];
  __syncthreads();
  #pragma unroll
  for (int i = 0; i < 32; i += 8)
    dst[(size_t)(c0 + ty + i) * R + r0 + tx] = f2bf(tile[tx][ty + i]);
}

// ---------------- ring-4 counted-vmcnt GEMM: C = A[M,768] @ Bt[N,768]^T ----------------
// 128x128 tile, BK=32, 4 LDS slots (16KB each: A 8KB + B 8KB), 4 waves.
// Pipeline: stage tile t+2 -> vmcnt(4) -> s_barrier -> ds_read(swz) -> 16 MFMA.
// Swizzle: LDS[r][b] = global[r][b ^ ((r&3)<<4)]  (64B rows, kills 8-way conflict).
// MODE 0: qkv epilogue (relu+eps -> qbf,kbf; vT pack). MODE 1: bias -> float C.
template <int MODE>
__global__ __launch_bounds__(256) void gemm_ring(const ushort_t* __restrict__ A,
                                                 const ushort_t* __restrict__ Bt,
                                                 ushort_t* __restrict__ qbf,
                                                 ushort_t* __restrict__ kbf,
                                                 ushort_t* __restrict__ vTbf,
                                                 const float* __restrict__ bias,
                                                 float* __restrict__ C) {
  const int K = DIM, Kb = DIM * 2;
  const int N = (MODE == 0) ? 3 * DIM : DIM;
  const int nbn = N / 128;
  const int NT = K / 32;              // 24
  __shared__ __align__(16) char lds[4 * 16384];

  int bid = blockIdx.x;
  int qd = gridDim.x >> 3;
  int wid = (bid & 7) * qd + (bid >> 3);
  int bm = wid / nbn, bn = wid % nbn;
  int row0 = bm * 128, col0 = bn * 128;
  int t = threadIdx.x;
  int lane = t & 63, wave = t >> 6;
  int wr = wave >> 1, wc = wave & 1;

  const char* Ag = (const char*)(A + (size_t)row0 * K);
  const char* Bg = (const char*)(Bt + (size_t)col0 * K);

  // per-thread stage offsets (2 calls x {A,B} per tile = 4 vmem ops/wave)
  int o0 = t * 16;            // call 0: rows 0..63
  int o1 = 4096 + t * 16;     // call 1: rows 64..127
  int r0s = o0 >> 6, r1s = o1 >> 6;
  int sb0 = (o0 & 63) ^ ((r0s & 3) << 4);
  int sb1 = (o1 & 63) ^ ((r1s & 3) << 4);
  size_t ga0 = (size_t)r0s * Kb + sb0;
  size_t ga1 = (size_t)r1s * Kb + sb1;

  // fragment read base
  int fr = lane & 15, fkb = (lane >> 4) << 4;
  int sw = fkb ^ ((fr & 3) << 4);
  int aoff = (wr * 64 + fr) * 64 + sw;      // + m*1024
  int boff = (wc * 64 + fr) * 64 + sw;      // + n*1024

  #define STAGE(tile, slot)                                            \
    do {                                                               \
      char* sb = lds + ((slot) << 14);                                 \
      gload_lds16(Ag + ga0 + (tile) * 64, sb + o0);                    \
      gload_lds16(Ag + ga1 + (tile) * 64, sb + o1);                    \
      gload_lds16(Bg + ga0 + (tile) * 64, sb + 8192 + o0);             \
      gload_lds16(Bg + ga1 + (tile) * 64, sb + 8192 + o1);             \
    } while (0)

  STAGE(0, 0);
  STAGE(1, 1);

  f32x4 acc[4][4] = {};
  #pragma unroll 2
  for (int kt = 0; kt < NT; ++kt) {
    if (kt + 2 < NT) STAGE(kt + 2, (kt + 2) & 3);
    if (kt < NT - 1) asm volatile("s_waitcnt vmcnt(4)" ::: "memory");
    else             asm volatile("s_waitcnt vmcnt(0)" ::: "memory");
    __builtin_amdgcn_s_barrier();
    const char* As = lds + ((kt & 3) << 14);
    const char* Bs = As + 8192;
    short8v a[4], b[4];
    #pragma unroll
    for (int m = 0; m < 4; ++m) a[m] = *(const short8v*)(As + aoff + m * 1024);
    #pragma unroll
    for (int n = 0; n < 4; ++n) b[n] = *(const short8v*)(Bs + boff + n * 1024);
    __builtin_amdgcn_s_setprio(1);
    #pragma unroll
    for (int m = 0; m < 4; ++m)
      #pragma unroll
      for (int n = 0; n < 4; ++n)
        acc[m][n] = __builtin_amdgcn_mfma_f32_16x16x32_bf16(a[m], b[n], acc[m][n], 0, 0, 0);
    __builtin_amdgcn_s_setprio(0);
  }
  #undef STAGE

  int rbase = row0 + wr * 64 + ((lane >> 4) << 2);
  int cbase = col0 + wc * 64 + fr;
  if constexpr (MODE == 0) {
    #pragma unroll
    for (int m = 0; m < 4; ++m) {
      int r0r = rbase + m * 16;
      #pragma unroll
      for (int n = 0; n < 4; ++n) {
        int c = cbase + n * 16;
        if (c < DIM) {
          #pragma unroll
          for (int j = 0; j < 4; ++j)
            qbf[(size_t)(r0r + j) * DIM + c] = f2bf(fmaxf(acc[m][n][j], 0.0f) + 1e-6f);
        } else if (c < 2 * DIM) {
          #pragma unroll
          for (int j = 0; j < 4; ++j)
            kbf[(size_t)(r0r + j) * DIM + (c - DIM)] = f2bf(fmaxf(acc[m][n][j], 0.0f) + 1e-6f);
        } else {
          int ch = c - 2 * DIM;
          int hh = ch >> 6, e = ch & 63;
          int bb = r0r >> 8, rr = r0r & 255;
          us4 pk;
          #pragma unroll
          for (int j = 0; j < 4; ++j) pk[j] = f2bf(acc[m][n][j]);
          *(us4*)&vTbf[((((size_t)bb * HEADS + hh) * 64 + e) << 8) + rr] = pk;
        }
      }
    }
  } else {
    #pragma unroll
    for (int m = 0; m < 4; ++m) {
      #pragma unroll
      for (int n = 0; n < 4; ++n) {
        int c = cbase + n * 16;
        float bz = bias[c];
        #pragma unroll
        for (int j = 0; j < 4; ++j)
          C[(size_t)(rbase + m * 16 + j) * N + c] = acc[m][n][j] + bz;
      }
    }
  }
}

// ---------------- fused attention middle: per (b,h), full MFMA ----------------
__global__ __launch_bounds__(512) void attn_fused(const ushort_t* __restrict__ qbf,
                                                  const ushort_t* __restrict__ kbf,
                                                  const ushort_t* __restrict__ vTbf,
                                                  const float* __restrict__ wp,
                                                  ushort_t* __restrict__ attnO) {
  __shared__ __align__(16) char lds[65536];
  int bh = blockIdx.x;
  int b = bh / HEADS, h = bh % HEADS;
  int t = threadIdx.x;
  int lane = t & 63, wave = t >> 6;
  int wr = wave >> 2, wc = wave & 3;
  int fr = lane & 15, fkb = (lane >> 4) << 4;

  const char* qg = (const char*)(qbf + ((size_t)b * 256) * DIM + h * 64);
  const char* kg = (const char*)(kbf + ((size_t)b * 256) * DIM + h * 64);
  const char* vg = (const char*)(vTbf + ((size_t)bh << 14));

  for (int q4 = 0; q4 < 4; ++q4) {
    #pragma unroll
    for (int is = 0; is < 4; ++is) {
      int o = is * 8192 + t * 16;
      int r = o >> 7;
      int byt = (o & 127) ^ ((r & 7) << 4);
      gload_lds16(kg + (size_t)r * (DIM * 2) + byt, lds + o);
    }
    {
      int o = t * 16;
      int r = o >> 7;
      int byt = (o & 127) ^ ((r & 7) << 4);
      gload_lds16(qg + (size_t)(q4 * 64 + r) * (DIM * 2) + byt, lds + 32768 + o);
    }
    __syncthreads();
    f32x4 accA[2][4] = {};
    {
      short8v af[2][2], bfv[4][2];
      #pragma unroll
      for (int mt = 0; mt < 2; ++mt)
        #pragma unroll
        for (int ks = 0; ks < 2; ++ks) {
          int r = wr * 32 + mt * 16 + fr;
          int kb = ks * 64 + fkb;
          af[mt][ks] = *(const short8v*)(lds + 32768 + r * 128 + (kb ^ ((r & 7) << 4)));
        }
      #pragma unroll
      for (int nt = 0; nt < 4; ++nt)
        #pragma unroll
        for (int ks = 0; ks < 2; ++ks) {
          int c = wc * 64 + nt * 16 + fr;
          int kb = ks * 64 + fkb;
          bfv[nt][ks] = *(const short8v*)(lds + c * 128 + (kb ^ ((c & 7) << 4)));
        }
      #pragma unroll
      for (int mt = 0; mt < 2; ++mt)
        #pragma unroll
        for (int nt = 0; nt < 4; ++nt)
          #pragma unroll
          for (int ks = 0; ks < 2; ++ks)
            accA[mt][nt] = __builtin_amdgcn_mfma_f32_16x16x32_bf16(af[mt][ks], bfv[nt][ks],
                                                                   accA[mt][nt], 0, 0, 0);
    }
    ushort_t sv[2][4][4];
    #pragma unroll
    for (int mt = 0; mt < 2; ++mt)
      #pragma unroll
      for (int nt = 0; nt < 4; ++nt) {
        float wpf = wp[(q4 * 4 + wr * 2 + mt) * 16 + (wc * 4 + nt)];
        #pragma unroll
        for (int j = 0; j < 4; ++j) sv[mt][nt][j] = f2bf(accA[mt][nt][j] * wpf);
      }
    __syncthreads();
    #pragma unroll
    for (int mt = 0; mt < 2; ++mt)
      #pragma unroll
      for (int nt = 0; nt < 4; ++nt)
        #pragma unroll
        for (int j = 0; j < 4; ++j) {
          int rs = wr * 32 + mt * 16 + ((lane >> 4) << 2) + j;
          int cs = wc * 64 + nt * 16 + fr;
          *(ushort_t*)(lds + 32768 + rs * 512 + ((cs * 2) ^ ((rs & 7) << 4))) = sv[mt][nt][j];
        }
    #pragma unroll
    for (int is = 0; is < 4; ++is) {
      int o = is * 8192 + t * 16;
      int e = o >> 9;
      int byt = (o & 511) ^ ((e & 7) << 4);
      gload_lds16(vg + e * 512 + byt, lds + o);
    }
    __syncthreads();
    f32x4 accB[2] = {{0.f,0.f,0.f,0.f},{0.f,0.f,0.f,0.f}};
    #pragma unroll
    for (int ks = 0; ks < 8; ++ks) {
      int kb = ks * 64 + fkb;
      int e = wc * 16 + fr;
      short8v bv = *(const short8v*)(lds + e * 512 + (kb ^ ((e & 7) << 4)));
      #pragma unroll
      for (int mt = 0; mt < 2; ++mt) {
        int r = wr * 32 + mt * 16 + fr;
        short8v av = *(const short8v*)(lds + 32768 + r * 512 + (kb ^ ((r & 7) << 4)));
        accB[mt] = __builtin_amdgcn_mfma_f32_16x16x32_bf16(av, bv, accB[mt], 0, 0, 0);
      }
    }
    #pragma unroll
    for (int mt = 0; mt < 2; ++mt) {
      int row = b * 256 + q4 * 64 + wr * 32 + mt * 16 + ((lane >> 4) << 2);
      int col = h * 64 + wc * 16 + fr;
      #pragma unroll
      for (int j = 0; j < 4; ++j)
        attnO[(size_t)(row + j) * DIM + col] = f2bf(accB[mt][j]);
    }
    __syncthreads();
  }
}

extern "C" void kernel_launch(void* const* d_in, const int* in_sizes, int n_in,
                              void* d_out, int out_size, void* d_ws, size_t ws_size,
                              hipStream_t stream) {
  const float* x    = (const float*)d_in[0];
  const float* g    = (const float*)d_in[1];
  const float* be   = (const float*)d_in[2];
  const float* wqkv = (const float*)d_in[3];
  const float* wout = (const float*)d_in[4];
  const float* bout = (const float*)d_in[5];
  const float* wp   = (const float*)d_in[6];
  float* out = (float*)d_out;

  char* w = (char*)d_ws;
  const size_t SZ = (size_t)TOK * DIM * 2;
  ushort_t* qbf   = (ushort_t*)(w);
  ushort_t* kbf   = (ushort_t*)(w + SZ);
  ushort_t* vTbf  = (ushort_t*)(w + 2 * SZ);
  ushort_t* xn    = (ushort_t*)(w + 3 * SZ);
  ushort_t* wqkvT = (ushort_t*)(w + 4 * SZ);
  ushort_t* woutT = (ushort_t*)(w + 4 * SZ + 3538944);
  ushort_t* attnO = xn;

  dim3 gt1(3 * DIM / 32, DIM / 32);
  convT<<<gt1, 256, 0, stream>>>(wqkv, wqkvT, DIM, 3 * DIM);
  dim3 gt2(DIM / 32, DIM / 32);
  convT<<<gt2, 256, 0, stream>>>(wout, woutT, DIM, DIM);

  ln_kernel<<<TOK, 256, 0, stream>>>(x, g, be, xn);

  gemm_ring<0><<<(TOK / 128) * (3 * DIM / 128), 256, 0, stream>>>(
      xn, wqkvT, qbf, kbf, vTbf, nullptr, nullptr);

  attn_fused<<<128 * HEADS, 512, 0, stream>>>(qbf, kbf, vTbf, wp, attnO);

  gemm_ring<1><<<(TOK / 128) * (DIM / 128), 256, 0, stream>>>(
      attnO, woutT, nullptr, nullptr, nullptr, bout, out);
}

// Round 5
// 321.303 us; speedup vs baseline: 8.1297x; 1.0381x over previous
//
#include <hip/hip_runtime.h>

#define DIM 768
#define HEADS 12
#define TOK 32768

typedef unsigned short ushort_t;
typedef __attribute__((ext_vector_type(8))) short short8v;   // 8 bf16
typedef __attribute__((ext_vector_type(4))) float f32x4;
typedef __attribute__((ext_vector_type(4))) unsigned short us4;

__device__ __forceinline__ ushort_t f2bf(float x) {
  union { float f; unsigned u; } c; c.f = x;
  unsigned r = (c.u + 0x7FFFu + ((c.u >> 16) & 1u)) >> 16;
  return (ushort_t)r;
}

__device__ __forceinline__ void gload_lds16(const void* g, void* l) {
  __builtin_amdgcn_global_load_lds((const __attribute__((address_space(1))) void*)g,
                                   (__attribute__((address_space(3))) void*)l, 16, 0, 0);
}

// ---------------- LayerNorm -> bf16 ----------------
__global__ __launch_bounds__(256) void ln_kernel(const float* __restrict__ x,
                                                 const float* __restrict__ g,
                                                 const float* __restrict__ be,
                                                 ushort_t* __restrict__ xn) {
  int t = blockIdx.x;
  int tid = threadIdx.x;
  const float* row = x + (size_t)t * DIM;
  float v0 = row[tid], v1 = row[tid + 256], v2 = row[tid + 512];
  float s  = v0 + v1 + v2;
  float sq = v0 * v0 + v1 * v1 + v2 * v2;
  #pragma unroll
  for (int off = 32; off; off >>= 1) {
    s  += __shfl_down(s, off);
    sq += __shfl_down(sq, off);
  }
  __shared__ float ls[4], lq[4];
  int wid = tid >> 6, lane = tid & 63;
  if (lane == 0) { ls[wid] = s; lq[wid] = sq; }
  __syncthreads();
  s  = ls[0] + ls[1] + ls[2] + ls[3];
  sq = lq[0] + lq[1] + lq[2] + lq[3];
  float mu  = s * (1.0f / DIM);
  float var = sq * (1.0f / DIM) - mu * mu;
  float rs  = rsqrtf(var + 1e-5f);
  ushort_t* orow = xn + (size_t)t * DIM;
  orow[tid]       = f2bf((v0 - mu) * rs * g[tid]       + be[tid]);
  orow[tid + 256] = f2bf((v1 - mu) * rs * g[tid + 256] + be[tid + 256]);
  orow[tid + 512] = f2bf((v2 - mu) * rs * g[tid + 512] + be[tid + 512]);
}

// ---------------- weight transpose + bf16: dst[c][r] = bf16(src[r][c]) ----------------
__global__ __launch_bounds__(256) void convT(const float* __restrict__ src,
                                             ushort_t* __restrict__ dst, int R, int Ccol) {
  __shared__ float tile[32][33];
  int c0 = blockIdx.x * 32, r0 = blockIdx.y * 32;
  int tx = threadIdx.x & 31, ty = threadIdx.x >> 5;
  #pragma unroll
  for (int i = 0; i < 32; i += 8)
    tile[ty + i][tx] = src[(size_t)(r0 + ty + i) * Ccol + c0 + tx];
  __syncthreads();
  #pragma unroll
  for (int i = 0; i < 32; i += 8)
    dst[(size_t)(c0 + ty + i) * R + r0 + tx] = f2bf(tile[tx][ty + i]);
}

// ---------------- 256x256-tile ring-4 counted-vmcnt GEMM ----------------
// 512 threads = 8 waves (2 Mrow x 4 Ncol), wave tile 128x64, BK=32.
// LDS: 4 slots x (A 16KB + B 16KB) = 128KB dynamic.
// Pipeline per step: [stage t+2 -> vmcnt(8)] barrier; swz ds_read; 32 MFMA.
// MODE 0: qkv epilogue (relu+eps -> qbf,kbf; vT pack). MODE 1: bias -> float C.
template <int MODE>
__global__ __launch_bounds__(512, 2) void gemm_big(const ushort_t* __restrict__ A,
                                                   const ushort_t* __restrict__ Bt,
                                                   ushort_t* __restrict__ qbf,
                                                   ushort_t* __restrict__ kbf,
                                                   ushort_t* __restrict__ vTbf,
                                                   const float* __restrict__ bias,
                                                   float* __restrict__ C) {
  extern __shared__ __align__(16) char lds[];
  const int K = DIM, Kb = DIM * 2;
  const int N = (MODE == 0) ? 3 * DIM : DIM;
  const int nbn = N / 256;
  const int NT = K / 32;              // 24

  int bid = blockIdx.x;
  int qd = gridDim.x >> 3;
  int wid = (bid & 7) * qd + (bid >> 3);
  int bm = wid / nbn, bn = wid % nbn;
  int row0 = bm * 256, col0 = bn * 256;
  int t = threadIdx.x;
  int lane = t & 63, wave = t >> 6;
  int wr = wave >> 2, wcol = wave & 3;

  const char* Ag = (const char*)(A + (size_t)row0 * K);
  const char* Bg = (const char*)(Bt + (size_t)col0 * K);

  // staging: 512 threads cover a 16KB region in two 8KB calls.
  // region layout: row r (0..255) at r*64; 16B slot s swizzled s^=(r&3).
  int o0 = t * 16, o1 = 8192 + t * 16;
  int ra0 = o0 >> 6, ra1 = o1 >> 6;
  int cb0 = (o0 & 63) ^ ((ra0 & 3) << 4);
  int cb1 = (o1 & 63) ^ ((ra1 & 3) << 4);
  size_t ga0 = (size_t)ra0 * Kb + cb0;
  size_t ga1 = (size_t)ra1 * Kb + cb1;

  // fragment read base (swizzle matches staging: 16B slot ^ (row&3))
  int fr = lane & 15, fkb = (lane >> 4) << 4;
  int sw = fkb ^ ((fr & 3) << 4);
  int aoff = (wr * 128 + fr) * 64 + sw;             // + m*1024, m<8
  int boff = 16384 + (wcol * 64 + fr) * 64 + sw;    // + n*1024, n<4

  #define STAGE(tile, slot)                                            \
    do {                                                               \
      char* sb = lds + ((slot) * 32768);                               \
      size_t kb_ = (size_t)(tile) * 64;                                \
      gload_lds16(Ag + ga0 + kb_, sb + o0);                            \
      gload_lds16(Ag + ga1 + kb_, sb + o1);                            \
      gload_lds16(Bg + ga0 + kb_, sb + 16384 + o0);                    \
      gload_lds16(Bg + ga1 + kb_, sb + 16384 + o1);                    \
    } while (0)

  STAGE(0, 0);
  STAGE(1, 1);

  f32x4 acc[8][4] = {};
  for (int kt = 0; kt < NT; ++kt) {
    if (kt + 2 < NT) {
      STAGE(kt + 2, (kt + 2) & 3);
      asm volatile("s_waitcnt vmcnt(8)" ::: "memory");   // tile kt landed; kt+1,kt+2 in flight
    } else if (kt + 2 == NT) {
      asm volatile("s_waitcnt vmcnt(4)" ::: "memory");   // tile kt landed; kt+1 in flight
    } else {
      asm volatile("s_waitcnt vmcnt(0)" ::: "memory");   // last tile
    }
    __builtin_amdgcn_s_barrier();
    const char* As = lds + ((kt & 3) * 32768);
    short8v a[8], b[4];
    #pragma unroll
    for (int m = 0; m < 8; ++m) a[m] = *(const short8v*)(As + aoff + m * 1024);
    #pragma unroll
    for (int n = 0; n < 4; ++n) b[n] = *(const short8v*)(As + boff + n * 1024);
    __builtin_amdgcn_s_setprio(1);
    #pragma unroll
    for (int m = 0; m < 8; ++m)
      #pragma unroll
      for (int n = 0; n < 4; ++n)
        acc[m][n] = __builtin_amdgcn_mfma_f32_16x16x32_bf16(a[m], b[n], acc[m][n], 0, 0, 0);
    __builtin_amdgcn_s_setprio(0);
  }
  #undef STAGE

  int rbase = row0 + wr * 128 + ((lane >> 4) << 2);
  int cbase = col0 + wcol * 64 + fr;
  if constexpr (MODE == 0) {
    #pragma unroll
    for (int m = 0; m < 8; ++m) {
      int r0r = rbase + m * 16;
      #pragma unroll
      for (int n = 0; n < 4; ++n) {
        int c = cbase + n * 16;
        if (c < DIM) {
          #pragma unroll
          for (int j = 0; j < 4; ++j)
            qbf[(size_t)(r0r + j) * DIM + c] = f2bf(fmaxf(acc[m][n][j], 0.0f) + 1e-6f);
        } else if (c < 2 * DIM) {
          #pragma unroll
          for (int j = 0; j < 4; ++j)
            kbf[(size_t)(r0r + j) * DIM + (c - DIM)] = f2bf(fmaxf(acc[m][n][j], 0.0f) + 1e-6f);
        } else {
          int ch = c - 2 * DIM;
          int hh = ch >> 6, e = ch & 63;
          int bb = r0r >> 8, rr = r0r & 255;
          us4 pk;
          #pragma unroll
          for (int j = 0; j < 4; ++j) pk[j] = f2bf(acc[m][n][j]);
          *(us4*)&vTbf[((((size_t)bb * HEADS + hh) * 64 + e) << 8) + rr] = pk;
        }
      }
    }
  } else {
    #pragma unroll
    for (int m = 0; m < 8; ++m) {
      #pragma unroll
      for (int n = 0; n < 4; ++n) {
        int c = cbase + n * 16;
        float bz = bias[c];
        #pragma unroll
        for (int j = 0; j < 4; ++j)
          C[(size_t)(rbase + m * 16 + j) * N + c] = acc[m][n][j] + bz;
      }
    }
  }
}

// ---------------- fused attention middle: per (b,h), full MFMA ----------------
__global__ __launch_bounds__(512) void attn_fused(const ushort_t* __restrict__ qbf,
                                                  const ushort_t* __restrict__ kbf,
                                                  const ushort_t* __restrict__ vTbf,
                                                  const float* __restrict__ wp,
                                                  ushort_t* __restrict__ attnO) {
  __shared__ __align__(16) char lds[65536];
  int bh = blockIdx.x;
  int b = bh / HEADS, h = bh % HEADS;
  int t = threadIdx.x;
  int lane = t & 63, wave = t >> 6;
  int wr = wave >> 2, wc = wave & 3;
  int fr = lane & 15, fkb = (lane >> 4) << 4;

  const char* qg = (const char*)(qbf + ((size_t)b * 256) * DIM + h * 64);
  const char* kg = (const char*)(kbf + ((size_t)b * 256) * DIM + h * 64);
  const char* vg = (const char*)(vTbf + ((size_t)bh << 14));

  for (int q4 = 0; q4 < 4; ++q4) {
    #pragma unroll
    for (int is = 0; is < 4; ++is) {
      int o = is * 8192 + t * 16;
      int r = o >> 7;
      int byt = (o & 127) ^ ((r & 7) << 4);
      gload_lds16(kg + (size_t)r * (DIM * 2) + byt, lds + o);
    }
    {
      int o = t * 16;
      int r = o >> 7;
      int byt = (o & 127) ^ ((r & 7) << 4);
      gload_lds16(qg + (size_t)(q4 * 64 + r) * (DIM * 2) + byt, lds + 32768 + o);
    }
    __syncthreads();
    f32x4 accA[2][4] = {};
    {
      short8v af[2][2], bfv[4][2];
      #pragma unroll
      for (int mt = 0; mt < 2; ++mt)
        #pragma unroll
        for (int ks = 0; ks < 2; ++ks) {
          int r = wr * 32 + mt * 16 + fr;
          int kb = ks * 64 + fkb;
          af[mt][ks] = *(const short8v*)(lds + 32768 + r * 128 + (kb ^ ((r & 7) << 4)));
        }
      #pragma unroll
      for (int nt = 0; nt < 4; ++nt)
        #pragma unroll
        for (int ks = 0; ks < 2; ++ks) {
          int c = wc * 64 + nt * 16 + fr;
          int kb = ks * 64 + fkb;
          bfv[nt][ks] = *(const short8v*)(lds + c * 128 + (kb ^ ((c & 7) << 4)));
        }
      #pragma unroll
      for (int mt = 0; mt < 2; ++mt)
        #pragma unroll
        for (int nt = 0; nt < 4; ++nt)
          #pragma unroll
          for (int ks = 0; ks < 2; ++ks)
            accA[mt][nt] = __builtin_amdgcn_mfma_f32_16x16x32_bf16(af[mt][ks], bfv[nt][ks],
                                                                   accA[mt][nt], 0, 0, 0);
    }
    ushort_t sv[2][4][4];
    #pragma unroll
    for (int mt = 0; mt < 2; ++mt)
      #pragma unroll
      for (int nt = 0; nt < 4; ++nt) {
        float wpf = wp[(q4 * 4 + wr * 2 + mt) * 16 + (wc * 4 + nt)];
        #pragma unroll
        for (int j = 0; j < 4; ++j) sv[mt][nt][j] = f2bf(accA[mt][nt][j] * wpf);
      }
    __syncthreads();
    #pragma unroll
    for (int mt = 0; mt < 2; ++mt)
      #pragma unroll
      for (int nt = 0; nt < 4; ++nt)
        #pragma unroll
        for (int j = 0; j < 4; ++j) {
          int rs = wr * 32 + mt * 16 + ((lane >> 4) << 2) + j;
          int cs = wc * 64 + nt * 16 + fr;
          *(ushort_t*)(lds + 32768 + rs * 512 + ((cs * 2) ^ ((rs & 7) << 4))) = sv[mt][nt][j];
        }
    #pragma unroll
    for (int is = 0; is < 4; ++is) {
      int o = is * 8192 + t * 16;
      int e = o >> 9;
      int byt = (o & 511) ^ ((e & 7) << 4);
      gload_lds16(vg + e * 512 + byt, lds + o);
    }
    __syncthreads();
    f32x4 accB[2] = {{0.f,0.f,0.f,0.f},{0.f,0.f,0.f,0.f}};
    #pragma unroll
    for (int ks = 0; ks < 8; ++ks) {
      int kb = ks * 64 + fkb;
      int e = wc * 16 + fr;
      short8v bv = *(const short8v*)(lds + e * 512 + (kb ^ ((e & 7) << 4)));
      #pragma unroll
      for (int mt = 0; mt < 2; ++mt) {
        int r = wr * 32 + mt * 16 + fr;
        short8v av = *(const short8v*)(lds + 32768 + r * 512 + (kb ^ ((r & 7) << 4)));
        accB[mt] = __builtin_amdgcn_mfma_f32_16x16x32_bf16(av, bv, accB[mt], 0, 0, 0);
      }
    }
    #pragma unroll
    for (int mt = 0; mt < 2; ++mt) {
      int row = b * 256 + q4 * 64 + wr * 32 + mt * 16 + ((lane >> 4) << 2);
      int col = h * 64 + wc * 16 + fr;
      #pragma unroll
      for (int j = 0; j < 4; ++j)
        attnO[(size_t)(row + j) * DIM + col] = f2bf(accB[mt][j]);
    }
    __syncthreads();
  }
}

extern "C" void kernel_launch(void* const* d_in, const int* in_sizes, int n_in,
                              void* d_out, int out_size, void* d_ws, size_t ws_size,
                              hipStream_t stream) {
  const float* x    = (const float*)d_in[0];
  const float* g    = (const float*)d_in[1];
  const float* be   = (const float*)d_in[2];
  const float* wqkv = (const float*)d_in[3];
  const float* wout = (const float*)d_in[4];
  const float* bout = (const float*)d_in[5];
  const float* wp   = (const float*)d_in[6];
  float* out = (float*)d_out;

  char* w = (char*)d_ws;
  const size_t SZ = (size_t)TOK * DIM * 2;
  ushort_t* qbf   = (ushort_t*)(w);
  ushort_t* kbf   = (ushort_t*)(w + SZ);
  ushort_t* vTbf  = (ushort_t*)(w + 2 * SZ);
  ushort_t* xn    = (ushort_t*)(w + 3 * SZ);
  ushort_t* wqkvT = (ushort_t*)(w + 4 * SZ);
  ushort_t* woutT = (ushort_t*)(w + 4 * SZ + 3538944);
  ushort_t* attnO = xn;

  // allow 128KB dynamic LDS (idempotent, deterministic)
  (void)hipFuncSetAttribute(reinterpret_cast<const void*>(&gemm_big<0>),
                            hipFuncAttributeMaxDynamicSharedMemorySize, 131072);
  (void)hipFuncSetAttribute(reinterpret_cast<const void*>(&gemm_big<1>),
                            hipFuncAttributeMaxDynamicSharedMemorySize, 131072);

  dim3 gt1(3 * DIM / 32, DIM / 32);
  convT<<<gt1, 256, 0, stream>>>(wqkv, wqkvT, DIM, 3 * DIM);
  dim3 gt2(DIM / 32, DIM / 32);
  convT<<<gt2, 256, 0, stream>>>(wout, woutT, DIM, DIM);

  ln_kernel<<<TOK, 256, 0, stream>>>(x, g, be, xn);

  gemm_big<0><<<(TOK / 256) * (3 * DIM / 256), 512, 131072, stream>>>(
      xn, wqkvT, qbf, kbf, vTbf, nullptr, nullptr);

  attn_fused<<<128 * HEADS, 512, 0, stream>>>(qbf, kbf, vTbf, wp, attnO);

  gemm_big<1><<<(TOK / 256) * (DIM / 256), 512, 131072, stream>>>(
      attnO, woutT, nullptr, nullptr, nullptr, bout, out);
}

// Round 6
// 309.291 us; speedup vs baseline: 8.4455x; 1.0388x over previous
//
#include <hip/hip_runtime.h>

#define DIM 768
#define HEADS 12
#define TOK 32768

typedef unsigned short ushort_t;
typedef __attribute__((ext_vector_type(8))) short short8v;   // 8 bf16
typedef __attribute__((ext_vector_type(4))) float f32x4;
typedef __attribute__((ext_vector_type(4))) unsigned short us4;

__device__ __forceinline__ ushort_t f2bf(float x) {
  union { float f; unsigned u; } c; c.f = x;
  unsigned r = (c.u + 0x7FFFu + ((c.u >> 16) & 1u)) >> 16;
  return (ushort_t)r;
}

__device__ __forceinline__ void gload_lds16(const void* g, void* l) {
  __builtin_amdgcn_global_load_lds((const __attribute__((address_space(1))) void*)g,
                                   (__attribute__((address_space(3))) void*)l, 16, 0, 0);
}

// ---------------- LayerNorm -> bf16 ----------------
__global__ __launch_bounds__(256) void ln_kernel(const float* __restrict__ x,
                                                 const float* __restrict__ g,
                                                 const float* __restrict__ be,
                                                 ushort_t* __restrict__ xn) {
  int t = blockIdx.x;
  int tid = threadIdx.x;
  const float* row = x + (size_t)t * DIM;
  float v0 = row[tid], v1 = row[tid + 256], v2 = row[tid + 512];
  float s  = v0 + v1 + v2;
  float sq = v0 * v0 + v1 * v1 + v2 * v2;
  #pragma unroll
  for (int off = 32; off; off >>= 1) {
    s  += __shfl_down(s, off);
    sq += __shfl_down(sq, off);
  }
  __shared__ float ls[4], lq[4];
  int wid = tid >> 6, lane = tid & 63;
  if (lane == 0) { ls[wid] = s; lq[wid] = sq; }
  __syncthreads();
  s  = ls[0] + ls[1] + ls[2] + ls[3];
  sq = lq[0] + lq[1] + lq[2] + lq[3];
  float mu  = s * (1.0f / DIM);
  float var = sq * (1.0f / DIM) - mu * mu;
  float rs  = rsqrtf(var + 1e-5f);
  ushort_t* orow = xn + (size_t)t * DIM;
  orow[tid]       = f2bf((v0 - mu) * rs * g[tid]       + be[tid]);
  orow[tid + 256] = f2bf((v1 - mu) * rs * g[tid + 256] + be[tid + 256]);
  orow[tid + 512] = f2bf((v2 - mu) * rs * g[tid + 512] + be[tid + 512]);
}

// ---------------- weight transpose + bf16: dst[c][r] = bf16(src[r][c]) ----------------
__global__ __launch_bounds__(256) void convT(const float* __restrict__ src,
                                             ushort_t* __restrict__ dst, int R, int Ccol) {
  __shared__ float tile[32][33];
  int c0 = blockIdx.x * 32, r0 = blockIdx.y * 32;
  int tx = threadIdx.x & 31, ty = threadIdx.x >> 5;
  #pragma unroll
  for (int i = 0; i < 32; i += 8)
    tile[ty + i][tx] = src[(size_t)(r0 + ty + i) * Ccol + c0 + tx];
  __syncthreads();
  #pragma unroll
  for (int i = 0; i < 32; i += 8)
    dst[(size_t)(c0 + ty + i) * R + r0 + tx] = f2bf(tile[tx][ty + i]);
}

// ---------------- 256x256 8-phase GEMM (m201-style), K=768, BK=64 ----------------
// 512 thr = 8 waves (2Mrow x 4Ncol), wave tile 128x64. 2 dbufs x (A 32KB + B 32KB) = 128KB.
// Iter = 2 K-tiles (dbuf0 then dbuf1), 4 quadrant-phases each; per phase:
// {ds_reads, one half-tile stage} -> barrier -> lgkmcnt(0) -> 16 MFMA -> [gate] -> barrier.
// Gates: vmcnt(6) at P4/P8 only (= 3 half-stages in flight). Swizzle byte^=((row&7)<<4).
template <int MODE>
__global__ __launch_bounds__(512, 2) void gemm_8ph(const ushort_t* __restrict__ A,
                                                   const ushort_t* __restrict__ Bt,
                                                   ushort_t* __restrict__ qbf,
                                                   ushort_t* __restrict__ kbf,
                                                   ushort_t* __restrict__ vTbf,
                                                   const float* __restrict__ bias,
                                                   float* __restrict__ C) {
  extern __shared__ __align__(16) char lds[];
  const int K = DIM, Kb = DIM * 2;                  // 1536 bytes/row
  const int N = (MODE == 0) ? 3 * DIM : DIM;
  const int nbn = N / 256;
  const size_t GHalf = (size_t)64 * Kb;

  int bid = blockIdx.x;
  int qd = gridDim.x >> 3;
  int wid = (bid & 7) * qd + (bid >> 3);
  int bm = wid / nbn, bn = wid % nbn;
  int row0 = bm * 256, col0 = bn * 256;
  int t = threadIdx.x;
  int lane = t & 63, wave = t >> 6;
  int wr = wave >> 2, wc = wave & 3;

  const char* Ag = (const char*)A + (size_t)row0 * Kb;
  const char* Bg = (const char*)Bt + (size_t)col0 * Kb;

  // staging: per-thread linear LDS offset o0; inverse-swizzled global source
  int o0 = t * 16;
  int sr = o0 >> 7;                                  // 0..63
  int skb = (o0 & 127) ^ ((sr & 7) << 4);
  size_t goff = (size_t)sr * Kb + skb;

  #define STG(Gbase, Lbase, kt)                                               \
    do {                                                                      \
      gload_lds16((Gbase) + goff + (size_t)(kt) * 128, lds + (Lbase) + o0);   \
      gload_lds16((Gbase) + goff + GHalf + (size_t)(kt) * 128,                \
                  lds + (Lbase) + o0 + 8192);                                 \
    } while (0)

  // fragment read offsets (swizzled)
  int fr = lane & 15, fkb = (lane >> 4) << 4;
  int swz = (fr & 7) << 4;
  int kb0 = fkb ^ swz;
  int kb1 = (64 + fkb) ^ swz;
  int laA = (wr * 128 + fr) * 128;                   // + mq*8192 + mi*2048
  int laB = 32768 + (wc * 64 + fr) * 128;            // + nq*4096 + ni*2048

  #define LOAD_A(dst, dbase, mq)                                              \
    _Pragma("unroll") for (int mi = 0; mi < 4; ++mi) {                        \
      dst[mi][0] = *(const short8v*)(lds + (dbase) + laA + (mq)*8192 + mi*2048 + kb0); \
      dst[mi][1] = *(const short8v*)(lds + (dbase) + laA + (mq)*8192 + mi*2048 + kb1); \
    }
  #define LOAD_B(dst, dbase, nq)                                              \
    _Pragma("unroll") for (int ni = 0; ni < 2; ++ni) {                        \
      dst[ni][0] = *(const short8v*)(lds + (dbase) + laB + (nq)*4096 + ni*2048 + kb0); \
      dst[ni][1] = *(const short8v*)(lds + (dbase) + laB + (nq)*4096 + ni*2048 + kb1); \
    }
  #define MFMA16(av, bv, mq, nq)                                              \
    do {                                                                      \
      __builtin_amdgcn_s_setprio(1);                                          \
      _Pragma("unroll") for (int mi = 0; mi < 4; ++mi)                        \
        _Pragma("unroll") for (int ni = 0; ni < 2; ++ni) {                    \
          acc[(mq)*4+mi][(nq)*2+ni] = __builtin_amdgcn_mfma_f32_16x16x32_bf16(\
              av[mi][0], bv[ni][0], acc[(mq)*4+mi][(nq)*2+ni], 0, 0, 0);      \
          acc[(mq)*4+mi][(nq)*2+ni] = __builtin_amdgcn_mfma_f32_16x16x32_bf16(\
              av[mi][1], bv[ni][1], acc[(mq)*4+mi][(nq)*2+ni], 0, 0, 0);      \
        }                                                                     \
      __builtin_amdgcn_s_setprio(0);                                          \
    } while (0)
  #define FENCE asm volatile("" ::: "memory")
  #define BAR do { FENCE; __builtin_amdgcn_s_barrier(); FENCE; } while (0)
  #define LGK asm volatile("s_waitcnt lgkmcnt(0)" ::: "memory")

  // prologue: t0 full (8 ops) + t1 {A-lo,A-hi,B-lo} (6 ops); t1.B-hi comes at it0.P1
  STG(Ag, 0, 0);  STG(Ag + 128 * Kb, 16384, 0);
  STG(Bg, 32768, 0);  STG(Bg + 128 * Kb, 49152, 0);
  STG(Ag, 65536, 1);  STG(Ag + 128 * Kb, 65536 + 16384, 1);
  STG(Bg, 65536 + 32768, 1);
  asm volatile("s_waitcnt vmcnt(6)" ::: "memory");
  __builtin_amdgcn_s_barrier();

  f32x4 acc[8][4] = {};
  for (int it = 0; it < 6; ++it) {
    const int d0 = 0, d1 = 65536;
    int t1k = 2 * it + 1, t2k = 2 * it + 2, t3k = 2 * it + 3;
    bool st = (it < 5);
    short8v ar[4][2], a2[4][2], br[2][2], b2[2][2];
    // P1: dbuf0 quadrant (0,0); stage t1.B-hi -> dbuf1
    LOAD_A(ar, d0, 0); LOAD_B(br, d0, 0);
    STG(Bg + 128 * Kb, d1 + 49152, t1k);
    BAR; LGK; MFMA16(ar, br, 0, 0); BAR;
    // P2: (1,0)
    LOAD_A(a2, d0, 1);
    BAR; LGK; MFMA16(a2, br, 1, 0); BAR;
    // P3: (0,1); stage t2.A -> dbuf0 (A dead since P2)
    LOAD_B(b2, d0, 1);
    if (st) { STG(Ag, d0, t2k); STG(Ag + 128 * Kb, d0 + 16384, t2k); }
    BAR; LGK; MFMA16(ar, b2, 0, 1); BAR;
    // P4: (1,1); stage t2.B-lo; GATE (t1 fully landed before P5 reads dbuf1)
    if (st) STG(Bg, d0 + 32768, t2k);
    BAR; LGK; MFMA16(a2, b2, 1, 1);
    if (st) asm volatile("s_waitcnt vmcnt(6)" ::: "memory");
    else    asm volatile("s_waitcnt vmcnt(0)" ::: "memory");
    BAR;
    // P5: dbuf1 (0,0); stage t2.B-hi -> dbuf0 (B dead since P3)
    LOAD_A(ar, d1, 0); LOAD_B(br, d1, 0);
    if (st) STG(Bg + 128 * Kb, d0 + 49152, t2k);
    BAR; LGK; MFMA16(ar, br, 0, 0); BAR;
    // P6: (1,0)
    LOAD_A(a2, d1, 1);
    BAR; LGK; MFMA16(a2, br, 1, 0); BAR;
    // P7: (0,1); stage t3.A -> dbuf1 (A dead since P6)
    LOAD_B(b2, d1, 1);
    if (st) { STG(Ag, d1, t3k); STG(Ag + 128 * Kb, d1 + 16384, t3k); }
    BAR; LGK; MFMA16(ar, b2, 0, 1); BAR;
    // P8: (1,1); stage t3.B-lo; GATE (t2 fully landed before next P1 reads dbuf0)
    if (st) STG(Bg, d1 + 32768, t3k);
    BAR; LGK; MFMA16(a2, b2, 1, 1);
    if (st) asm volatile("s_waitcnt vmcnt(6)" ::: "memory");
    BAR;
  }
  #undef STG
  #undef LOAD_A
  #undef LOAD_B
  #undef MFMA16

  int rbase = row0 + wr * 128 + ((lane >> 4) << 2);
  int cbase = col0 + wc * 64 + fr;
  if constexpr (MODE == 0) {
    #pragma unroll
    for (int m = 0; m < 8; ++m) {
      int r0r = rbase + m * 16;
      #pragma unroll
      for (int n = 0; n < 4; ++n) {
        int c = cbase + n * 16;
        if (c < DIM) {
          #pragma unroll
          for (int j = 0; j < 4; ++j)
            qbf[(size_t)(r0r + j) * DIM + c] = f2bf(fmaxf(acc[m][n][j], 0.0f) + 1e-6f);
        } else if (c < 2 * DIM) {
          #pragma unroll
          for (int j = 0; j < 4; ++j)
            kbf[(size_t)(r0r + j) * DIM + (c - DIM)] = f2bf(fmaxf(acc[m][n][j], 0.0f) + 1e-6f);
        } else {
          int ch = c - 2 * DIM;
          int hh = ch >> 6, e = ch & 63;
          int bb = r0r >> 8, rr = r0r & 255;
          us4 pk;
          #pragma unroll
          for (int j = 0; j < 4; ++j) pk[j] = f2bf(acc[m][n][j]);
          *(us4*)&vTbf[((((size_t)bb * HEADS + hh) * 64 + e) << 8) + rr] = pk;
        }
      }
    }
  } else {
    #pragma unroll
    for (int m = 0; m < 8; ++m) {
      #pragma unroll
      for (int n = 0; n < 4; ++n) {
        int c = cbase + n * 16;
        float bz = bias[c];
        #pragma unroll
        for (int j = 0; j < 4; ++j)
          C[(size_t)(rbase + m * 16 + j) * N + c] = acc[m][n][j] + bz;
      }
    }
  }
}

// ---------------- fused attention middle: per (b,h), full MFMA ----------------
__global__ __launch_bounds__(512) void attn_fused(const ushort_t* __restrict__ qbf,
                                                  const ushort_t* __restrict__ kbf,
                                                  const ushort_t* __restrict__ vTbf,
                                                  const float* __restrict__ wp,
                                                  ushort_t* __restrict__ attnO) {
  __shared__ __align__(16) char lds[65536];
  int bh = blockIdx.x;
  int b = bh / HEADS, h = bh % HEADS;
  int t = threadIdx.x;
  int lane = t & 63, wave = t >> 6;
  int wr = wave >> 2, wc = wave & 3;
  int fr = lane & 15, fkb = (lane >> 4) << 4;

  const char* qg = (const char*)(qbf + ((size_t)b * 256) * DIM + h * 64);
  const char* kg = (const char*)(kbf + ((size_t)b * 256) * DIM + h * 64);
  const char* vg = (const char*)(vTbf + ((size_t)bh << 14));

  for (int q4 = 0; q4 < 4; ++q4) {
    #pragma unroll
    for (int is = 0; is < 4; ++is) {
      int o = is * 8192 + t * 16;
      int r = o >> 7;
      int byt = (o & 127) ^ ((r & 7) << 4);
      gload_lds16(kg + (size_t)r * (DIM * 2) + byt, lds + o);
    }
    {
      int o = t * 16;
      int r = o >> 7;
      int byt = (o & 127) ^ ((r & 7) << 4);
      gload_lds16(qg + (size_t)(q4 * 64 + r) * (DIM * 2) + byt, lds + 32768 + o);
    }
    __syncthreads();
    f32x4 accA[2][4] = {};
    {
      short8v af[2][2], bfv[4][2];
      #pragma unroll
      for (int mt = 0; mt < 2; ++mt)
        #pragma unroll
        for (int ks = 0; ks < 2; ++ks) {
          int r = wr * 32 + mt * 16 + fr;
          int kb = ks * 64 + fkb;
          af[mt][ks] = *(const short8v*)(lds + 32768 + r * 128 + (kb ^ ((r & 7) << 4)));
        }
      #pragma unroll
      for (int nt = 0; nt < 4; ++nt)
        #pragma unroll
        for (int ks = 0; ks < 2; ++ks) {
          int c = wc * 64 + nt * 16 + fr;
          int kb = ks * 64 + fkb;
          bfv[nt][ks] = *(const short8v*)(lds + c * 128 + (kb ^ ((c & 7) << 4)));
        }
      #pragma unroll
      for (int mt = 0; mt < 2; ++mt)
        #pragma unroll
        for (int nt = 0; nt < 4; ++nt)
          #pragma unroll
          for (int ks = 0; ks < 2; ++ks)
            accA[mt][nt] = __builtin_amdgcn_mfma_f32_16x16x32_bf16(af[mt][ks], bfv[nt][ks],
                                                                   accA[mt][nt], 0, 0, 0);
    }
    ushort_t sv[2][4][4];
    #pragma unroll
    for (int mt = 0; mt < 2; ++mt)
      #pragma unroll
      for (int nt = 0; nt < 4; ++nt) {
        float wpf = wp[(q4 * 4 + wr * 2 + mt) * 16 + (wc * 4 + nt)];
        #pragma unroll
        for (int j = 0; j < 4; ++j) sv[mt][nt][j] = f2bf(accA[mt][nt][j] * wpf);
      }
    __syncthreads();
    #pragma unroll
    for (int mt = 0; mt < 2; ++mt)
      #pragma unroll
      for (int nt = 0; nt < 4; ++nt)
        #pragma unroll
        for (int j = 0; j < 4; ++j) {
          int rs = wr * 32 + mt * 16 + ((lane >> 4) << 2) + j;
          int cs = wc * 64 + nt * 16 + fr;
          *(ushort_t*)(lds + 32768 + rs * 512 + ((cs * 2) ^ ((rs & 7) << 4))) = sv[mt][nt][j];
        }
    #pragma unroll
    for (int is = 0; is < 4; ++is) {
      int o = is * 8192 + t * 16;
      int e = o >> 9;
      int byt = (o & 511) ^ ((e & 7) << 4);
      gload_lds16(vg + e * 512 + byt, lds + o);
    }
    __syncthreads();
    f32x4 accB[2] = {{0.f,0.f,0.f,0.f},{0.f,0.f,0.f,0.f}};
    #pragma unroll
    for (int ks = 0; ks < 8; ++ks) {
      int kb = ks * 64 + fkb;
      int e = wc * 16 + fr;
      short8v bv = *(const short8v*)(lds + e * 512 + (kb ^ ((e & 7) << 4)));
      #pragma unroll
      for (int mt = 0; mt < 2; ++mt) {
        int r = wr * 32 + mt * 16 + fr;
        short8v av = *(const short8v*)(lds + 32768 + r * 512 + (kb ^ ((r & 7) << 4)));
        accB[mt] = __builtin_amdgcn_mfma_f32_16x16x32_bf16(av, bv, accB[mt], 0, 0, 0);
      }
    }
    #pragma unroll
    for (int mt = 0; mt < 2; ++mt) {
      int row = b * 256 + q4 * 64 + wr * 32 + mt * 16 + ((lane >> 4) << 2);
      int col = h * 64 + wc * 16 + fr;
      #pragma unroll
      for (int j = 0; j < 4; ++j)
        attnO[(size_t)(row + j) * DIM + col] = f2bf(accB[mt][j]);
    }
    __syncthreads();
  }
}

extern "C" void kernel_launch(void* const* d_in, const int* in_sizes, int n_in,
                              void* d_out, int out_size, void* d_ws, size_t ws_size,
                              hipStream_t stream) {
  const float* x    = (const float*)d_in[0];
  const float* g    = (const float*)d_in[1];
  const float* be   = (const float*)d_in[2];
  const float* wqkv = (const float*)d_in[3];
  const float* wout = (const float*)d_in[4];
  const float* bout = (const float*)d_in[5];
  const float* wp   = (const float*)d_in[6];
  float* out = (float*)d_out;

  char* w = (char*)d_ws;
  const size_t SZ = (size_t)TOK * DIM * 2;
  ushort_t* qbf   = (ushort_t*)(w);
  ushort_t* kbf   = (ushort_t*)(w + SZ);
  ushort_t* vTbf  = (ushort_t*)(w + 2 * SZ);
  ushort_t* xn    = (ushort_t*)(w + 3 * SZ);
  ushort_t* wqkvT = (ushort_t*)(w + 4 * SZ);
  ushort_t* woutT = (ushort_t*)(w + 4 * SZ + 3538944);
  ushort_t* attnO = xn;

  (void)hipFuncSetAttribute(reinterpret_cast<const void*>(&gemm_8ph<0>),
                            hipFuncAttributeMaxDynamicSharedMemorySize, 131072);
  (void)hipFuncSetAttribute(reinterpret_cast<const void*>(&gemm_8ph<1>),
                            hipFuncAttributeMaxDynamicSharedMemorySize, 131072);

  dim3 gt1(3 * DIM / 32, DIM / 32);
  convT<<<gt1, 256, 0, stream>>>(wqkv, wqkvT, DIM, 3 * DIM);
  dim3 gt2(DIM / 32, DIM / 32);
  convT<<<gt2, 256, 0, stream>>>(wout, woutT, DIM, DIM);

  ln_kernel<<<TOK, 256, 0, stream>>>(x, g, be, xn);

  gemm_8ph<0><<<(TOK / 256) * (3 * DIM / 256), 512, 131072, stream>>>(
      xn, wqkvT, qbf, kbf, vTbf, nullptr, nullptr);

  attn_fused<<<128 * HEADS, 512, 0, stream>>>(qbf, kbf, vTbf, wp, attnO);

  gemm_8ph<1><<<(TOK / 256) * (DIM / 256), 512, 131072, stream>>>(
      attnO, woutT, nullptr, nullptr, nullptr, bout, out);
}

// Round 7
// 301.743 us; speedup vs baseline: 8.6567x; 1.0250x over previous
//
#include <hip/hip_runtime.h>

#define DIM 768
#define HEADS 12
#define TOK 32768

typedef unsigned short ushort_t;
typedef __attribute__((ext_vector_type(8))) short short8v;   // 8 bf16
typedef __attribute__((ext_vector_type(4))) float f32x4;
typedef __attribute__((ext_vector_type(4))) unsigned short us4;

__device__ __forceinline__ ushort_t f2bf(float x) {
  union { float f; unsigned u; } c; c.f = x;
  unsigned r = (c.u + 0x7FFFu + ((c.u >> 16) & 1u)) >> 16;
  return (ushort_t)r;
}

__device__ __forceinline__ void gload_lds16(const void* g, void* l) {
  __builtin_amdgcn_global_load_lds((const __attribute__((address_space(1))) void*)g,
                                   (__attribute__((address_space(3))) void*)l, 16, 0, 0);
}

#define FENCE asm volatile("" ::: "memory")
#define BARRIER do { FENCE; __builtin_amdgcn_s_barrier(); FENCE; } while (0)
#define LGK0 asm volatile("s_waitcnt lgkmcnt(0)" ::: "memory")

// ---------------- LayerNorm -> bf16 ----------------
__global__ __launch_bounds__(256) void ln_kernel(const float* __restrict__ x,
                                                 const float* __restrict__ g,
                                                 const float* __restrict__ be,
                                                 ushort_t* __restrict__ xn) {
  int t = blockIdx.x;
  int tid = threadIdx.x;
  const float* row = x + (size_t)t * DIM;
  float v0 = row[tid], v1 = row[tid + 256], v2 = row[tid + 512];
  float s  = v0 + v1 + v2;
  float sq = v0 * v0 + v1 * v1 + v2 * v2;
  #pragma unroll
  for (int off = 32; off; off >>= 1) {
    s  += __shfl_down(s, off);
    sq += __shfl_down(sq, off);
  }
  __shared__ float ls[4], lq[4];
  int wid = tid >> 6, lane = tid & 63;
  if (lane == 0) { ls[wid] = s; lq[wid] = sq; }
  __syncthreads();
  s  = ls[0] + ls[1] + ls[2] + ls[3];
  sq = lq[0] + lq[1] + lq[2] + lq[3];
  float mu  = s * (1.0f / DIM);
  float var = sq * (1.0f / DIM) - mu * mu;
  float rs  = rsqrtf(var + 1e-5f);
  ushort_t* orow = xn + (size_t)t * DIM;
  orow[tid]       = f2bf((v0 - mu) * rs * g[tid]       + be[tid]);
  orow[tid + 256] = f2bf((v1 - mu) * rs * g[tid + 256] + be[tid + 256]);
  orow[tid + 512] = f2bf((v2 - mu) * rs * g[tid + 512] + be[tid + 512]);
}

// ---------------- weight transpose + bf16: dst[c][r] = bf16(src[r][c]) ----------------
__global__ __launch_bounds__(256) void convT(const float* __restrict__ src,
                                             ushort_t* __restrict__ dst, int R, int Ccol) {
  __shared__ float tile[32][33];
  int c0 = blockIdx.x * 32, r0 = blockIdx.y * 32;
  int tx = threadIdx.x & 31, ty = threadIdx.x >> 5;
  #pragma unroll
  for (int i = 0; i < 32; i += 8)
    tile[ty + i][tx] = src[(size_t)(r0 + ty + i) * Ccol + c0 + tx];
  __syncthreads();
  #pragma unroll
  for (int i = 0; i < 32; i += 8)
    dst[(size_t)(c0 + ty + i) * R + r0 + tx] = f2bf(tile[tx][ty + i]);
}

// ---------------- GEMM1: 256x256 8-phase, K=768, BK=64 (MODE qkv epilogue) ----------------
__global__ __launch_bounds__(512, 2) void gemm_8ph(const ushort_t* __restrict__ A,
                                                   const ushort_t* __restrict__ Bt,
                                                   ushort_t* __restrict__ qbf,
                                                   ushort_t* __restrict__ kbf,
                                                   ushort_t* __restrict__ vTbf) {
  extern __shared__ __align__(16) char lds[];
  const int Kb = DIM * 2;
  const int N = 3 * DIM;
  const int nbn = N / 256;   // 9
  const size_t GHalf = (size_t)64 * Kb;

  int bid = blockIdx.x;
  int qd = gridDim.x >> 3;
  int wid = (bid & 7) * qd + (bid >> 3);
  int bm = wid / nbn, bn = wid % nbn;
  int row0 = bm * 256, col0 = bn * 256;
  int t = threadIdx.x;
  int lane = t & 63, wave = t >> 6;
  int wr = wave >> 2, wc = wave & 3;

  const char* Ag = (const char*)A + (size_t)row0 * Kb;
  const char* Bg = (const char*)Bt + (size_t)col0 * Kb;

  int o0 = t * 16;
  int sr = o0 >> 7;
  int skb = (o0 & 127) ^ ((sr & 7) << 4);
  size_t goff = (size_t)sr * Kb + skb;

  #define STG(Gbase, Lbase, kt)                                               \
    do {                                                                      \
      gload_lds16((Gbase) + goff + (size_t)(kt) * 128, lds + (Lbase) + o0);   \
      gload_lds16((Gbase) + goff + GHalf + (size_t)(kt) * 128,                \
                  lds + (Lbase) + o0 + 8192);                                 \
    } while (0)

  int fr = lane & 15, fkb = (lane >> 4) << 4;
  int swz = (fr & 7) << 4;
  int kb0 = fkb ^ swz;
  int kb1 = (64 + fkb) ^ swz;
  int laA = (wr * 128 + fr) * 128;
  int laB = 32768 + (wc * 64 + fr) * 128;

  #define LOAD_A(dst, dbase, mq)                                              \
    _Pragma("unroll") for (int mi = 0; mi < 4; ++mi) {                        \
      dst[mi][0] = *(const short8v*)(lds + (dbase) + laA + (mq)*8192 + mi*2048 + kb0); \
      dst[mi][1] = *(const short8v*)(lds + (dbase) + laA + (mq)*8192 + mi*2048 + kb1); \
    }
  #define LOAD_B(dst, dbase, nq)                                              \
    _Pragma("unroll") for (int ni = 0; ni < 2; ++ni) {                        \
      dst[ni][0] = *(const short8v*)(lds + (dbase) + laB + (nq)*4096 + ni*2048 + kb0); \
      dst[ni][1] = *(const short8v*)(lds + (dbase) + laB + (nq)*4096 + ni*2048 + kb1); \
    }
  #define MFMA16(av, bv, mq, nq)                                              \
    do {                                                                      \
      __builtin_amdgcn_s_setprio(1);                                          \
      _Pragma("unroll") for (int mi = 0; mi < 4; ++mi)                        \
        _Pragma("unroll") for (int ni = 0; ni < 2; ++ni) {                    \
          acc[(mq)*4+mi][(nq)*2+ni] = __builtin_amdgcn_mfma_f32_16x16x32_bf16(\
              av[mi][0], bv[ni][0], acc[(mq)*4+mi][(nq)*2+ni], 0, 0, 0);      \
          acc[(mq)*4+mi][(nq)*2+ni] = __builtin_amdgcn_mfma_f32_16x16x32_bf16(\
              av[mi][1], bv[ni][1], acc[(mq)*4+mi][(nq)*2+ni], 0, 0, 0);      \
        }                                                                     \
      __builtin_amdgcn_s_setprio(0);                                          \
    } while (0)

  STG(Ag, 0, 0);  STG(Ag + 128 * Kb, 16384, 0);
  STG(Bg, 32768, 0);  STG(Bg + 128 * Kb, 49152, 0);
  STG(Ag, 65536, 1);  STG(Ag + 128 * Kb, 65536 + 16384, 1);
  STG(Bg, 65536 + 32768, 1);
  asm volatile("s_waitcnt vmcnt(6)" ::: "memory");
  __builtin_amdgcn_s_barrier();

  f32x4 acc[8][4] = {};
  for (int it = 0; it < 6; ++it) {
    const int d0 = 0, d1 = 65536;
    int t1k = 2 * it + 1, t2k = 2 * it + 2, t3k = 2 * it + 3;
    bool st = (it < 5);
    short8v ar[4][2], a2[4][2], br[2][2], b2[2][2];
    LOAD_A(ar, d0, 0); LOAD_B(br, d0, 0);
    STG(Bg + 128 * Kb, d1 + 49152, t1k);
    BARRIER; LGK0; MFMA16(ar, br, 0, 0); BARRIER;
    LOAD_A(a2, d0, 1);
    BARRIER; LGK0; MFMA16(a2, br, 1, 0); BARRIER;
    LOAD_B(b2, d0, 1);
    if (st) { STG(Ag, d0, t2k); STG(Ag + 128 * Kb, d0 + 16384, t2k); }
    BARRIER; LGK0; MFMA16(ar, b2, 0, 1); BARRIER;
    if (st) STG(Bg, d0 + 32768, t2k);
    BARRIER; LGK0; MFMA16(a2, b2, 1, 1);
    if (st) asm volatile("s_waitcnt vmcnt(6)" ::: "memory");
    else    asm volatile("s_waitcnt vmcnt(0)" ::: "memory");
    BARRIER;
    LOAD_A(ar, d1, 0); LOAD_B(br, d1, 0);
    if (st) STG(Bg + 128 * Kb, d0 + 49152, t2k);
    BARRIER; LGK0; MFMA16(ar, br, 0, 0); BARRIER;
    LOAD_A(a2, d1, 1);
    BARRIER; LGK0; MFMA16(a2, br, 1, 0); BARRIER;
    LOAD_B(b2, d1, 1);
    if (st) { STG(Ag, d1, t3k); STG(Ag + 128 * Kb, d1 + 16384, t3k); }
    BARRIER; LGK0; MFMA16(ar, b2, 0, 1); BARRIER;
    if (st) STG(Bg, d1 + 32768, t3k);
    BARRIER; LGK0; MFMA16(a2, b2, 1, 1);
    if (st) asm volatile("s_waitcnt vmcnt(6)" ::: "memory");
    BARRIER;
  }
  #undef STG
  #undef LOAD_A
  #undef LOAD_B
  #undef MFMA16

  int rbase = row0 + wr * 128 + ((lane >> 4) << 2);
  int cbase = col0 + wc * 64 + fr;
  #pragma unroll
  for (int m = 0; m < 8; ++m) {
    int r0r = rbase + m * 16;
    #pragma unroll
    for (int n = 0; n < 4; ++n) {
      int c = cbase + n * 16;
      if (c < DIM) {
        #pragma unroll
        for (int j = 0; j < 4; ++j)
          qbf[(size_t)(r0r + j) * DIM + c] = f2bf(fmaxf(acc[m][n][j], 0.0f) + 1e-6f);
      } else if (c < 2 * DIM) {
        #pragma unroll
        for (int j = 0; j < 4; ++j)
          kbf[(size_t)(r0r + j) * DIM + (c - DIM)] = f2bf(fmaxf(acc[m][n][j], 0.0f) + 1e-6f);
      } else {
        int ch = c - 2 * DIM;
        int hh = ch >> 6, e = ch & 63;
        int bb = r0r >> 8, rr = r0r & 255;
        us4 pk;
        #pragma unroll
        for (int j = 0; j < 4; ++j) pk[j] = f2bf(acc[m][n][j]);
        *(us4*)&vTbf[((((size_t)bb * HEADS + hh) * 64 + e) << 8) + rr] = pk;
      }
    }
  }
}

// ---------------- GEMM2: 256x128 8-phase, bias, fp32 out ----------------
__global__ __launch_bounds__(512, 2) void gemm_out8(const ushort_t* __restrict__ A,
                                                    const ushort_t* __restrict__ Bt,
                                                    const float* __restrict__ bias,
                                                    float* __restrict__ C) {
  extern __shared__ __align__(16) char lds[];
  const int Kb = DIM * 2;
  const int N = DIM;
  const int nbn = N / 128;   // 6
  const size_t GHalf = (size_t)64 * Kb;

  int bid = blockIdx.x;
  int qd = gridDim.x >> 3;   // 96
  int wid = (bid & 7) * qd + (bid >> 3);
  int bm = wid / nbn, bn = wid % nbn;
  int row0 = bm * 256, col0 = bn * 128;
  int t = threadIdx.x;
  int lane = t & 63, wave = t >> 6;
  int wr = wave >> 2, wc = wave & 3;

  const char* Ag = (const char*)A + (size_t)row0 * Kb;
  const char* Bg = (const char*)Bt + (size_t)col0 * Kb;

  int o0 = t * 16;
  int sr = o0 >> 7;
  int skb = (o0 & 127) ^ ((sr & 7) << 4);
  size_t goff = (size_t)sr * Kb + skb;

  // A stage: 16KB half-tile = 2 ops; B stage: 8KB half-tile = 1 op
  #define STGA(Gbase, Lbase, kt)                                              \
    do {                                                                      \
      gload_lds16((Gbase) + goff + (size_t)(kt) * 128, lds + (Lbase) + o0);   \
      gload_lds16((Gbase) + goff + GHalf + (size_t)(kt) * 128,                \
                  lds + (Lbase) + o0 + 8192);                                 \
    } while (0)
  #define STGB(Gbase, Lbase, kt)                                              \
    gload_lds16((Gbase) + goff + (size_t)(kt) * 128, lds + (Lbase) + o0)

  int fr = lane & 15, fkb = (lane >> 4) << 4;
  int swz = (fr & 7) << 4;
  int kb0 = fkb ^ swz;
  int kb1 = (64 + fkb) ^ swz;
  int laA = (wr * 128 + fr) * 128;                 // + mq*8192 + mi*2048
  int laB = 32768 + (wc * 32 + fr) * 128;          // + nq*2048

  #define LOAD_A(dst, dbase, mq)                                              \
    _Pragma("unroll") for (int mi = 0; mi < 4; ++mi) {                        \
      dst[mi][0] = *(const short8v*)(lds + (dbase) + laA + (mq)*8192 + mi*2048 + kb0); \
      dst[mi][1] = *(const short8v*)(lds + (dbase) + laA + (mq)*8192 + mi*2048 + kb1); \
    }
  #define LOAD_B(dst, dbase, nq)                                              \
    do {                                                                      \
      dst[0] = *(const short8v*)(lds + (dbase) + laB + (nq)*2048 + kb0);      \
      dst[1] = *(const short8v*)(lds + (dbase) + laB + (nq)*2048 + kb1);      \
    } while (0)
  #define MFMA8(av, bv, mq, nq)                                               \
    do {                                                                      \
      __builtin_amdgcn_s_setprio(1);                                          \
      _Pragma("unroll") for (int mi = 0; mi < 4; ++mi) {                      \
        acc[(mq)*4+mi][nq] = __builtin_amdgcn_mfma_f32_16x16x32_bf16(         \
            av[mi][0], bv[0], acc[(mq)*4+mi][nq], 0, 0, 0);                   \
        acc[(mq)*4+mi][nq] = __builtin_amdgcn_mfma_f32_16x16x32_bf16(         \
            av[mi][1], bv[1], acc[(mq)*4+mi][nq], 0, 0, 0);                   \
      }                                                                       \
      __builtin_amdgcn_s_setprio(0);                                          \
    } while (0)

  // LDS: dbuf0 @0 (A 32KB, B 16KB @+32768), dbuf1 @49152
  STGA(Ag, 0, 0);  STGA(Ag + 128 * Kb, 16384, 0);
  STGB(Bg, 32768, 0);  STGB(Bg + GHalf, 32768 + 8192, 0);
  STGA(Ag, 49152, 1);  STGA(Ag + 128 * Kb, 49152 + 16384, 1);
  STGB(Bg, 49152 + 32768, 1);
  asm volatile("s_waitcnt vmcnt(5)" ::: "memory");
  __builtin_amdgcn_s_barrier();

  f32x4 acc[8][2] = {};
  for (int it = 0; it < 6; ++it) {
    const int d0 = 0, d1 = 49152;
    int t1k = 2 * it + 1, t2k = 2 * it + 2, t3k = 2 * it + 3;
    bool st = (it < 5);
    short8v ar[4][2], a2[4][2], br[2], b2[2];
    // P1: (0,0); stage t1.B-hi -> dbuf1
    LOAD_A(ar, d0, 0); LOAD_B(br, d0, 0);
    STGB(Bg + GHalf, d1 + 32768 + 8192, t1k);
    BARRIER; LGK0; MFMA8(ar, br, 0, 0); BARRIER;
    // P2: (1,0)
    LOAD_A(a2, d0, 1);
    BARRIER; LGK0; MFMA8(a2, br, 1, 0); BARRIER;
    // P3: (0,1); stage t2.A -> dbuf0
    LOAD_B(b2, d0, 1);
    if (st) { STGA(Ag, d0, t2k); STGA(Ag + 128 * Kb, d0 + 16384, t2k); }
    BARRIER; LGK0; MFMA8(ar, b2, 0, 1); BARRIER;
    // P4: (1,1); stage t2.B-lo; GATE vmcnt(5)
    if (st) STGB(Bg, d0 + 32768, t2k);
    BARRIER; LGK0; MFMA8(a2, b2, 1, 1);
    if (st) asm volatile("s_waitcnt vmcnt(5)" ::: "memory");
    else    asm volatile("s_waitcnt vmcnt(0)" ::: "memory");
    BARRIER;
    // P5: dbuf1 (0,0); stage t2.B-hi -> dbuf0
    LOAD_A(ar, d1, 0); LOAD_B(br, d1, 0);
    if (st) STGB(Bg + GHalf, d0 + 32768 + 8192, t2k);
    BARRIER; LGK0; MFMA8(ar, br, 0, 0); BARRIER;
    // P6: (1,0)
    LOAD_A(a2, d1, 1);
    BARRIER; LGK0; MFMA8(a2, br, 1, 0); BARRIER;
    // P7: (0,1); stage t3.A -> dbuf1
    LOAD_B(b2, d1, 1);
    if (st) { STGA(Ag, d1, t3k); STGA(Ag + 128 * Kb, d1 + 16384, t3k); }
    BARRIER; LGK0; MFMA8(ar, b2, 0, 1); BARRIER;
    // P8: (1,1); stage t3.B-lo; GATE vmcnt(5)
    if (st) STGB(Bg, d1 + 32768, t3k);
    BARRIER; LGK0; MFMA8(a2, b2, 1, 1);
    if (st) asm volatile("s_waitcnt vmcnt(5)" ::: "memory");
    BARRIER;
  }
  #undef STGA
  #undef STGB
  #undef LOAD_A
  #undef LOAD_B
  #undef MFMA8

  int rbase = row0 + wr * 128 + ((lane >> 4) << 2);
  int cbase = col0 + wc * 32 + fr;
  #pragma unroll
  for (int m = 0; m < 8; ++m) {
    #pragma unroll
    for (int n = 0; n < 2; ++n) {
      int c = cbase + n * 16;
      float bz = bias[c];
      #pragma unroll
      for (int j = 0; j < 4; ++j)
        C[(size_t)(rbase + m * 16 + j) * N + c] = acc[m][n][j] + bz;
    }
  }
}

// ---------------- attention middle v2: persistent K+VT, swapped S-GEMM ----------------
// LDS: K [0,32K) 256x128B swz | VT [32K,64K) 64x512B swz | Q [64K,72K) 64x128B swz
//      | S' [72K,104K) 64x512B swz.  One (b,h) per block, 8 waves.
__global__ __launch_bounds__(512) void attn_fused(const ushort_t* __restrict__ qbf,
                                                  const ushort_t* __restrict__ kbf,
                                                  const ushort_t* __restrict__ vTbf,
                                                  const float* __restrict__ wp,
                                                  ushort_t* __restrict__ attnO) {
  extern __shared__ __align__(16) char lds[];
  const int QOFF = 65536, SOFF = 73728;
  int bh = blockIdx.x;
  int b = bh / HEADS, h = bh % HEADS;
  int t = threadIdx.x;
  int lane = t & 63, wave = t >> 6;
  int fr = lane & 15, fkb = (lane >> 4) << 4;
  int lg4 = (lane >> 4) << 2;

  const char* qg = (const char*)(qbf + ((size_t)b * 256) * DIM + h * 64);
  const char* kg = (const char*)(kbf + ((size_t)b * 256) * DIM + h * 64);
  const char* vg = (const char*)(vTbf + ((size_t)bh << 14));

  // ---- persistent stage: K (4 ops), VT (4 ops), Q0 (1 op) ----
  #pragma unroll
  for (int is = 0; is < 4; ++is) {
    int o = is * 8192 + t * 16;
    int r = o >> 7;
    int byt = (o & 127) ^ ((r & 7) << 4);
    gload_lds16(kg + (size_t)r * (DIM * 2) + byt, lds + o);
  }
  #pragma unroll
  for (int is = 0; is < 4; ++is) {
    int o = is * 8192 + t * 16;
    int e = o >> 9;
    int byt = (o & 511) ^ ((e & 7) << 4);
    gload_lds16(vg + e * 512 + byt, lds + 32768 + o);
  }
  {
    int o = t * 16;
    int r = o >> 7;
    int byt = (o & 127) ^ ((r & 7) << 4);
    gload_lds16(qg + (size_t)r * (DIM * 2) + byt, lds + QOFF + o);
  }
  asm volatile("s_waitcnt vmcnt(0)" ::: "memory");
  __builtin_amdgcn_s_barrier();

  // S-GEMM roles: wrs = scol quad (4), wcs = qrow half (2)
  int wrs = wave & 3, wcs = wave >> 2;
  // PV roles: wrp = qrow half (2), wcp = e quad (4)
  int wrp = wave >> 2, wcp = wave & 3;

  for (int q4 = 0; q4 < 4; ++q4) {
    // ---- S^T GEMM: D[scol][qrow] = sum_k K[scol][k] Q[qrow][k] ----
    f32x4 accA[4][2] = {};
    {
      short8v kf[4][2], qf[2][2];
      #pragma unroll
      for (int mi = 0; mi < 4; ++mi)
        #pragma unroll
        for (int ks = 0; ks < 2; ++ks) {
          int r = wrs * 64 + mi * 16 + fr;
          kf[mi][ks] = *(const short8v*)(lds + r * 128 + ((ks * 64 + fkb) ^ ((r & 7) << 4)));
        }
      #pragma unroll
      for (int ni = 0; ni < 2; ++ni)
        #pragma unroll
        for (int ks = 0; ks < 2; ++ks) {
          int r = wcs * 32 + ni * 16 + fr;
          qf[ni][ks] = *(const short8v*)(lds + QOFF + r * 128 + ((ks * 64 + fkb) ^ ((r & 7) << 4)));
        }
      #pragma unroll
      for (int mi = 0; mi < 4; ++mi)
        #pragma unroll
        for (int ni = 0; ni < 2; ++ni)
          #pragma unroll
          for (int ks = 0; ks < 2; ++ks)
            accA[mi][ni] = __builtin_amdgcn_mfma_f32_16x16x32_bf16(kf[mi][ks], qf[ni][ks],
                                                                   accA[mi][ni], 0, 0, 0);
    }
    BARRIER;   // Q,K reads + prev S' reads done block-wide
    // ---- write S' (b64, wp-scaled) + async-stage next Q ----
    #pragma unroll
    for (int mi = 0; mi < 4; ++mi)
      #pragma unroll
      for (int ni = 0; ni < 2; ++ni) {
        float wpf = wp[(q4 * 4 + wcs * 2 + ni) * 16 + wrs * 4 + mi];
        us4 pk;
        #pragma unroll
        for (int j = 0; j < 4; ++j) pk[j] = f2bf(accA[mi][ni][j] * wpf);
        int qrow = wcs * 32 + ni * 16 + fr;
        int sbyte = (wrs * 64 + mi * 16 + lg4) * 2;
        *(us4*)(lds + SOFF + qrow * 512 + (sbyte ^ ((qrow & 7) << 4))) = pk;
      }
    if (q4 < 3) {
      int o = t * 16;
      int r = o >> 7;
      int byt = (o & 127) ^ ((r & 7) << 4);
      gload_lds16(qg + (size_t)((q4 + 1) * 64 + r) * (DIM * 2) + byt, lds + QOFF + o);
    }
    LGK0;      // S' writes committed
    BARRIER;
    // ---- PV: out[qrow][e] = sum_scol S'[qrow][scol] VT[e][scol] ----
    f32x4 accB[2] = {{0.f,0.f,0.f,0.f},{0.f,0.f,0.f,0.f}};
    #pragma unroll
    for (int ks = 0; ks < 8; ++ks) {
      int kb = ks * 64 + fkb;
      int e = wcp * 16 + fr;
      short8v bv = *(const short8v*)(lds + 32768 + e * 512 + (kb ^ ((e & 7) << 4)));
      #pragma unroll
      for (int mt = 0; mt < 2; ++mt) {
        int r = wrp * 32 + mt * 16 + fr;
        short8v av = *(const short8v*)(lds + SOFF + r * 512 + (kb ^ ((r & 7) << 4)));
        accB[mt] = __builtin_amdgcn_mfma_f32_16x16x32_bf16(av, bv, accB[mt], 0, 0, 0);
      }
    }
    #pragma unroll
    for (int mt = 0; mt < 2; ++mt) {
      int row = b * 256 + q4 * 64 + wrp * 32 + mt * 16 + lg4;
      int col = h * 64 + wcp * 16 + fr;
      #pragma unroll
      for (int j = 0; j < 4; ++j)
        attnO[(size_t)(row + j) * DIM + col] = f2bf(accB[mt][j]);
    }
    if (q4 < 3) asm volatile("s_waitcnt vmcnt(8)" ::: "memory");  // Q (oldest) landed; 8 stores younger
    BARRIER;   // S' reads done -> next quarter may overwrite
  }
}

extern "C" void kernel_launch(void* const* d_in, const int* in_sizes, int n_in,
                              void* d_out, int out_size, void* d_ws, size_t ws_size,
                              hipStream_t stream) {
  const float* x    = (const float*)d_in[0];
  const float* g    = (const float*)d_in[1];
  const float* be   = (const float*)d_in[2];
  const float* wqkv = (const float*)d_in[3];
  const float* wout = (const float*)d_in[4];
  const float* bout = (const float*)d_in[5];
  const float* wp   = (const float*)d_in[6];
  float* out = (float*)d_out;

  char* w = (char*)d_ws;
  const size_t SZ = (size_t)TOK * DIM * 2;
  ushort_t* qbf   = (ushort_t*)(w);
  ushort_t* kbf   = (ushort_t*)(w + SZ);
  ushort_t* vTbf  = (ushort_t*)(w + 2 * SZ);
  ushort_t* xn    = (ushort_t*)(w + 3 * SZ);
  ushort_t* wqkvT = (ushort_t*)(w + 4 * SZ);
  ushort_t* woutT = (ushort_t*)(w + 4 * SZ + 3538944);
  ushort_t* attnO = xn;

  (void)hipFuncSetAttribute(reinterpret_cast<const void*>(&gemm_8ph),
                            hipFuncAttributeMaxDynamicSharedMemorySize, 131072);
  (void)hipFuncSetAttribute(reinterpret_cast<const void*>(&gemm_out8),
                            hipFuncAttributeMaxDynamicSharedMemorySize, 98304);
  (void)hipFuncSetAttribute(reinterpret_cast<const void*>(&attn_fused),
                            hipFuncAttributeMaxDynamicSharedMemorySize, 106496);

  dim3 gt1(3 * DIM / 32, DIM / 32);
  convT<<<gt1, 256, 0, stream>>>(wqkv, wqkvT, DIM, 3 * DIM);
  dim3 gt2(DIM / 32, DIM / 32);
  convT<<<gt2, 256, 0, stream>>>(wout, woutT, DIM, DIM);

  ln_kernel<<<TOK, 256, 0, stream>>>(x, g, be, xn);

  gemm_8ph<<<(TOK / 256) * (3 * DIM / 256), 512, 131072, stream>>>(
      xn, wqkvT, qbf, kbf, vTbf);

  attn_fused<<<128 * HEADS, 512, 106496, stream>>>(qbf, kbf, vTbf, wp, attnO);

  gemm_out8<<<(TOK / 256) * (DIM / 128), 512, 98304, stream>>>(
      attnO, woutT, bout, out);
}